// Round 2
// baseline (1737.128 us; speedup 1.0000x reference)
//
#include <hip/hip_runtime.h>
#include <hip/hip_bf16.h>

typedef __bf16 bf16x8 __attribute__((ext_vector_type(8)));
typedef float f32x4 __attribute__((ext_vector_type(4)));
typedef int i32x4 __attribute__((ext_vector_type(4)));

#define NB 32      // batch
#define NS 200     // seq
#define SP 256     // padded seq
#define ND 256     // per-head dim == model dim
#define NH 6
#define NL 8
#define NBS (NB*NS)      // 6400
#define NZ (NB*NH)       // 192
#define SLAB (SP*ND)     // 65536

using bf16 = __hip_bfloat16;

enum { EPI_F32 = 0, EPI_RELU_BF = 1, EPI_QKV = 2, EPI_PV = 3 };

__device__ __forceinline__ float b2f(bf16 x) { return __bfloat162float(x); }
__device__ __forceinline__ bf16 f2b(float x) { return __float2bfloat16(x); }

// ---------------------------------------------------------------------------
// Generic NT GEMM: C[m][n] = sum_k A[m][k] * B[n][k]   (A:[M,K], B:[N,K] bf16)
// 128x128 tile, 4 waves (2x2), each wave 64x64 via 4x4 frags of 16x16x32 MFMA.
// ---------------------------------------------------------------------------
template<int MODE>
__global__ __launch_bounds__(256)
void gemm_nt(const bf16* __restrict__ A,
             const bf16* __restrict__ Bm,
             int M, int N, int K,
             long long sAz, long long sBz,
             float* __restrict__ outF, long long sOz,
             bf16* __restrict__ outBf,
             const float* __restrict__ bias,
             const float* __restrict__ qkvb,
             const float* __restrict__ tnbp,
             bf16* __restrict__ Qb, bf16* __restrict__ Kb, bf16* __restrict__ Vb)
{
    __shared__ short As[128][40];
    __shared__ short Bs[128][40];
    const int tid = threadIdx.x;
    const int z   = blockIdx.z;
    const int m0  = blockIdx.y * 128;
    const int n0  = blockIdx.x * 128;
    const bf16* Ap = A  + (long long)z * sAz;
    const bf16* Bp = Bm + (long long)z * sBz;

    const int lane = tid & 63;
    const int wv   = tid >> 6;
    const int wm   = (wv >> 1) * 64;
    const int wn   = (wv & 1) * 64;
    const int fr   = lane & 15;
    const int kc   = (lane >> 4) * 8;

    f32x4 acc[4][4];
#pragma unroll
    for (int i = 0; i < 4; i++)
#pragma unroll
        for (int j = 0; j < 4; j++) acc[i][j] = (f32x4){0.f, 0.f, 0.f, 0.f};

    const int srow = tid >> 2;        // 0..63
    const int scol = (tid & 3) * 8;   // 0,8,16,24

    for (int k0 = 0; k0 < K; k0 += 32) {
        i32x4 a0 = *(const i32x4*)(Ap + (long long)(m0 + srow)      * K + (k0 + scol));
        i32x4 a1 = *(const i32x4*)(Ap + (long long)(m0 + srow + 64) * K + (k0 + scol));
        i32x4 b0 = *(const i32x4*)(Bp + (long long)(n0 + srow)      * K + (k0 + scol));
        i32x4 b1 = *(const i32x4*)(Bp + (long long)(n0 + srow + 64) * K + (k0 + scol));
        __syncthreads();
        *(i32x4*)&As[srow][scol]      = a0;
        *(i32x4*)&As[srow + 64][scol] = a1;
        *(i32x4*)&Bs[srow][scol]      = b0;
        *(i32x4*)&Bs[srow + 64][scol] = b1;
        __syncthreads();
        bf16x8 af[4], bfm[4];
#pragma unroll
        for (int i = 0; i < 4; i++) af[i]  = *(const bf16x8*)&As[wm + i*16 + fr][kc];
#pragma unroll
        for (int j = 0; j < 4; j++) bfm[j] = *(const bf16x8*)&Bs[wn + j*16 + fr][kc];
#pragma unroll
        for (int i = 0; i < 4; i++)
#pragma unroll
            for (int j = 0; j < 4; j++)
                acc[i][j] = __builtin_amdgcn_mfma_f32_16x16x32_bf16(af[i], bfm[j], acc[i][j], 0, 0, 0);
    }

    const int rq = (lane >> 4) * 4;
#pragma unroll
    for (int i = 0; i < 4; i++) {
#pragma unroll
        for (int j = 0; j < 4; j++) {
#pragma unroll
            for (int rg = 0; rg < 4; rg++) {
                int r = m0 + wm + i*16 + rq + rg;
                int c = n0 + wn + j*16 + fr;
                float v = acc[i][j][rg];
                if (MODE == EPI_F32) {
                    outF[(long long)z * sOz + (long long)r * N + c] = v;
                } else if (MODE == EPI_RELU_BF) {
                    v += bias[c];
                    outBf[(long long)r * N + c] = f2b(fmaxf(v, 0.f));
                } else if (MODE == EPI_QKV) {
                    int x  = c / 1536;
                    int c1 = c - x * 1536;
                    int hd = c1 >> 8;
                    int dd = c1 & 255;
                    int bb = r / 200;
                    int ss = r - bb * 200;
                    float bv = (c1 < 512) ? qkvb[x*512 + c1] : tnbp[x*1024 + c1 - 512];
                    v += bv;
                    long long off = ((long long)(bb*NH + hd) * SP + ss) * ND + dd;
                    bf16 hv = f2b(v);
                    if (x == 0) Qb[off] = hv; else if (x == 1) Kb[off] = hv; else Vb[off] = hv;
                } else { // EPI_PV: r = padded seq pos, c = head-dim
                    if (r < NS) {
                        int bb = z / NH;
                        int hh = z - bb * NH;
                        outBf[((long long)(bb*NS + r)) * (NH*ND) + hh*ND + c] = f2b(v);
                    }
                }
            }
        }
    }
}

// ---------------------------------------------------------------------------
__global__ void embed_kernel(const int* __restrict__ tokens, const float* __restrict__ tok_emb,
                             const float* __restrict__ pos_emb, float* __restrict__ hf,
                             bf16* __restrict__ hbf)
{
    long long id = (long long)blockIdx.x * 256 + threadIdx.x;
    if (id >= (long long)NBS * ND) return;
    long long r = id >> 8;
    int j = id & 255;
    int tk = tokens[r];
    int s  = (int)(r % NS);
    float v = tok_emb[(long long)tk * ND + j] + pos_emb[s * ND + j];
    hf[id]  = v;
    hbf[id] = f2b(v);
}

// out[l][c][r] = in[l][r][c]  (f32 -> bf16)
__global__ void transpose_w(const float* __restrict__ in, bf16* __restrict__ out,
                            int L, int R, int C, long long total)
{
    long long id = (long long)blockIdx.x * 256 + threadIdx.x;
    if (id >= total) return;
    int l = (int)(id / ((long long)R * C));
    long long rem = id - (long long)l * R * C;
    int c = (int)(rem / R);
    int r = (int)(rem - (long long)c * R);
    out[id] = f2b(in[((long long)l * R + r) * C + c]);
}

// wcat[lx][n][k] = wqkv[lx][k][n] for n<512  (cls heads, transposed)
__global__ void pack_cls(const float* __restrict__ wqkv, bf16* __restrict__ wcat)
{
    long long id = (long long)blockIdx.x * 256 + threadIdx.x;
    if (id >= 24ll * 512 * 256) return;
    int lx = (int)(id / (512 * 256));
    int rem = (int)(id - (long long)lx * 512 * 256);
    int n = rem >> 8;
    int k = rem & 255;
    wcat[((long long)lx * 1536 + n) * 256 + k] = f2b(wqkv[((long long)lx * 256 + k) * 512 + n]);
}

// wcat[lx][512+e][d] = sum_{m,n,o} a1[p,m,i] a2[q,m,n,j] a3[r,n,o,k] a4[t,o,l]
// with d=(p,q,r,t) base-4, e=((i*8+j)*8+k)*4+l
__global__ __launch_bounds__(256)
void build_wtns(const float* __restrict__ A1, const float* __restrict__ A2,
                const float* __restrict__ A3, const float* __restrict__ A4,
                bf16* __restrict__ wcat)
{
    int lx = blockIdx.x;                 // 0..23
    __shared__ float a1s[32], a2s[128], a3s[128], a4s[32];
    int t = threadIdx.x;
    if (t < 32)  { a1s[t] = A1[lx*32 + t]; a4s[t] = A4[lx*32 + t]; }
    if (t < 128) { a2s[t] = A2[lx*128 + t]; a3s[t] = A3[lx*128 + t]; }
    __syncthreads();
    int d = t;                           // 0..255
    int p = d >> 6, q = (d >> 4) & 3, rr = (d >> 2) & 3, tt = d & 3;
    for (int i = 0; i < 4; i++) {
        float w1_0 = a1s[(p*2 + 0)*4 + i];
        float w1_1 = a1s[(p*2 + 1)*4 + i];
        for (int j = 0; j < 8; j++) {
            float c1_0 = w1_0 * a2s[((q*2+0)*2+0)*8 + j] + w1_1 * a2s[((q*2+1)*2+0)*8 + j];
            float c1_1 = w1_0 * a2s[((q*2+0)*2+1)*8 + j] + w1_1 * a2s[((q*2+1)*2+1)*8 + j];
            for (int kk = 0; kk < 8; kk++) {
                float c2_0 = c1_0 * a3s[((rr*2+0)*2+0)*8 + kk] + c1_1 * a3s[((rr*2+1)*2+0)*8 + kk];
                float c2_1 = c1_0 * a3s[((rr*2+0)*2+1)*8 + kk] + c1_1 * a3s[((rr*2+1)*2+1)*8 + kk];
                for (int ll = 0; ll < 4; ll++) {
                    float sv = c2_0 * a4s[(tt*2 + 0)*4 + ll] + c2_1 * a4s[(tt*2 + 1)*4 + ll];
                    int e = ((i*8 + j)*8 + kk)*4 + ll;
                    wcat[((long long)lx * 1536 + 512 + e) * 256 + d] = f2b(sv);
                }
            }
        }
    }
}

// Vt[z][d][s] = (s<200) ? V[z][s][d] : 0
__global__ __launch_bounds__(256)
void transpose_v(const bf16* __restrict__ V, bf16* __restrict__ Vt)
{
    __shared__ bf16 tl[32][33];
    int z  = blockIdx.z;
    int s0 = blockIdx.y * 32, d0 = blockIdx.x * 32;
    const bf16* v = V  + (long long)z * SLAB;
    bf16*      vt = Vt + (long long)z * SLAB;
    int tx = threadIdx.x, ty = threadIdx.y;
#pragma unroll
    for (int i = 0; i < 4; i++) {
        int sl = ty*4 + i;
        int s  = s0 + sl;
        tl[sl][tx] = (s < NS) ? v[(long long)s * ND + d0 + tx] : f2b(0.f);
    }
    __syncthreads();
#pragma unroll
    for (int i = 0; i < 4; i++) {
        int dl = ty*4 + i;
        vt[(long long)(d0 + dl) * SP + s0 + tx] = tl[tx][dl];
    }
}

// softmax over keys with pad mask; scores fp32 -> probs bf16. One wave per row.
__global__ __launch_bounds__(256)
void softmax_kernel(const float* __restrict__ scores, bf16* __restrict__ probs,
                    const int* __restrict__ tokens)
{
    int z = blockIdx.y;
    int w = threadIdx.x >> 6, lane = threadIdx.x & 63;
    int i = blockIdx.x * 4 + w;
    int b = z / NH;
    long long base = (long long)z * SLAB + (long long)i * SP;
    float v[4];
#pragma unroll
    for (int c = 0; c < 4; c++) {
        int j = lane + 64*c;
        float x = scores[base + j] * 0.0625f;   // 1/sqrt(256)
        if (j >= NS) x = -1e30f;
        else if (tokens[b*NS + j] == 0) x += -1e9f;
        v[c] = x;
    }
    float m = fmaxf(fmaxf(v[0], v[1]), fmaxf(v[2], v[3]));
#pragma unroll
    for (int o = 32; o; o >>= 1) m = fmaxf(m, __shfl_xor(m, o));
    float e[4], s = 0.f;
#pragma unroll
    for (int c = 0; c < 4; c++) { e[c] = expf(v[c] - m); s += e[c]; }
#pragma unroll
    for (int o = 32; o; o >>= 1) s += __shfl_xor(s, o);
    float inv = 1.f / s;
#pragma unroll
    for (int c = 0; c < 4; c++) probs[base + lane + 64*c] = f2b(e[c] * inv);
}

// out = LN(resid + raw + bias) * g + b ; writes fp32 and bf16. One wave per row.
__global__ __launch_bounds__(256)
void ln_kernel(const float* __restrict__ raw, const float* __restrict__ bias,
               const float* __restrict__ resid,
               const float* __restrict__ g, const float* __restrict__ bb,
               float* __restrict__ outF, bf16* __restrict__ outBf)
{
    int w = threadIdx.x >> 6, lane = threadIdx.x & 63;
    long long r = (long long)blockIdx.x * 4 + w;
    long long base = r * ND;
    float x[4]; float s = 0.f;
#pragma unroll
    for (int c = 0; c < 4; c++) {
        int j = lane + 64*c;
        x[c] = resid[base + j] + raw[base + j] + bias[j];
        s += x[c];
    }
#pragma unroll
    for (int o = 32; o; o >>= 1) s += __shfl_xor(s, o);
    float mean = s * (1.f/256.f);
    float vs = 0.f;
#pragma unroll
    for (int c = 0; c < 4; c++) { float d = x[c] - mean; vs += d*d; }
#pragma unroll
    for (int o = 32; o; o >>= 1) vs += __shfl_xor(vs, o);
    float rs = rsqrtf(vs * (1.f/256.f) + 1e-6f);
#pragma unroll
    for (int c = 0; c < 4; c++) {
        int j = lane + 64*c;
        float y = (x[c] - mean) * rs * g[j] + bb[j];
        outF[base + j]  = y;
        outBf[base + j] = f2b(y);
    }
}

// ---------------------------------------------------------------------------
extern "C" void kernel_launch(void* const* d_in, const int* in_sizes, int n_in,
                              void* d_out, int out_size, void* d_ws, size_t ws_size,
                              hipStream_t stream)
{
    const int*   tokens  = (const int*)  d_in[0];
    const float* tok_emb = (const float*)d_in[1];
    const float* pos_emb = (const float*)d_in[2];
    const float* wqkv_w  = (const float*)d_in[3];
    const float* wqkv_b  = (const float*)d_in[4];
    const float* A1      = (const float*)d_in[5];
    const float* A2      = (const float*)d_in[6];
    const float* A3      = (const float*)d_in[7];
    const float* A4      = (const float*)d_in[8];
    const float* tnb     = (const float*)d_in[9];
    const float* out_w   = (const float*)d_in[10];
    const float* out_b   = (const float*)d_in[11];
    const float* ff1_w   = (const float*)d_in[12];
    const float* ff1_b   = (const float*)d_in[13];
    const float* ff2_w   = (const float*)d_in[14];
    const float* ff2_b   = (const float*)d_in[15];
    const float* ln1_g   = (const float*)d_in[16];
    const float* ln1_b   = (const float*)d_in[17];
    const float* ln2_g   = (const float*)d_in[18];
    const float* ln2_b   = (const float*)d_in[19];

    char* ws = (char*)d_ws;
    size_t off = 0;
    auto alloc = [&](size_t bytes) -> char* {
        char* p = ws + off;
        off += (bytes + 255) & ~(size_t)255;
        return p;
    };
    float* hf    = (float*)alloc((size_t)NBS * ND * 4);
    bf16*  hbf   = (bf16*) alloc((size_t)NBS * ND * 2);
    bf16*  wcat  = (bf16*) alloc(24ull * 1536 * 256 * 2);
    bf16*  owt   = (bf16*) alloc(8ull * 256 * 1536 * 2);
    bf16*  f1wt  = (bf16*) alloc(8ull * 1024 * 256 * 2);
    bf16*  f2wt  = (bf16*) alloc(8ull * 256 * 1024 * 2);
    bf16*  Qb    = (bf16*) alloc((size_t)NZ * SLAB * 2);
    bf16*  Kb    = (bf16*) alloc((size_t)NZ * SLAB * 2);
    bf16*  Vtb   = (bf16*) alloc((size_t)NZ * SLAB * 2);
    char*  Rreg  =         alloc((size_t)NZ * SLAB * 4);  // scores f32; reused for V / ctx / ffn
    bf16*  probs = (bf16*) alloc((size_t)NZ * SLAB * 2);
    float* raw   = (float*)alloc((size_t)NBS * ND * 4);
    float* out1f = (float*)alloc((size_t)NBS * ND * 4);
    bf16*  out1bf= (bf16*) alloc((size_t)NBS * ND * 2);
    if (off > ws_size) return;  // workspace too small -> visible failure (zeros)

    bf16*  Vb     = (bf16*)Rreg;                            // lives: qkv -> transpose_v
    float* scores = (float*)Rreg;                           // lives: scoresGEMM -> softmax
    bf16*  ctxg   = (bf16*)Rreg;                            // lives: PV -> outproj
    bf16*  ffn    = (bf16*)(Rreg + (size_t)NBS * 1536 * 2); // lives: ff1 -> ff2

    hipMemsetAsync(Qb, 0, (size_t)NZ * SLAB * 2, stream);
    hipMemsetAsync(Kb, 0, (size_t)NZ * SLAB * 2, stream);

    embed_kernel<<<NBS, 256, 0, stream>>>(tokens, tok_emb, pos_emb, hf, hbf);
    pack_cls<<<12288, 256, 0, stream>>>(wqkv_w, wcat);
    build_wtns<<<24, 256, 0, stream>>>(A1, A2, A3, A4, wcat);
    transpose_w<<<12288, 256, 0, stream>>>(out_w, owt, 8, 1536, 256, 8ll*1536*256);
    transpose_w<<<8192, 256, 0, stream>>>(ff1_w, f1wt, 8, 256, 1024, 8ll*256*1024);
    transpose_w<<<8192, 256, 0, stream>>>(ff2_w, f2wt, 8, 1024, 256, 8ll*1024*256);

    for (int l = 0; l < NL; l++) {
        // QKV projection (cls + tensor-network heads fused): [6400,256] @ [4608,256]^T
        gemm_nt<EPI_QKV><<<dim3(36, 50, 1), 256, 0, stream>>>(
            hbf, wcat + (long long)l * 3 * 1536 * 256, NBS, 4608, 256, 0, 0,
            nullptr, 0, nullptr, nullptr,
            wqkv_b + l * 3 * 512, tnb + l * 3 * 1024, Qb, Kb, Vb);
        transpose_v<<<dim3(8, 8, NZ), dim3(32, 8), 0, stream>>>(Vb, Vtb);
        // scores = Q @ K^T  (per b,h)
        gemm_nt<EPI_F32><<<dim3(2, 2, NZ), 256, 0, stream>>>(
            Qb, Kb, SP, SP, ND, SLAB, SLAB, scores, SLAB,
            nullptr, nullptr, nullptr, nullptr, nullptr, nullptr, nullptr);
        softmax_kernel<<<dim3(64, NZ), 256, 0, stream>>>(scores, probs, tokens);
        // ctx = P @ V  (per b,h), scattered to [b*s, h*256+d]
        gemm_nt<EPI_PV><<<dim3(2, 2, NZ), 256, 0, stream>>>(
            probs, Vtb, SP, SP, SP, SLAB, SLAB, nullptr, 0, ctxg,
            nullptr, nullptr, nullptr, nullptr, nullptr, nullptr);
        // out projection
        gemm_nt<EPI_F32><<<dim3(2, 50, 1), 256, 0, stream>>>(
            ctxg, owt + (long long)l * 256 * 1536, NBS, 256, 1536, 0, 0,
            raw, 0, nullptr, nullptr, nullptr, nullptr, nullptr, nullptr, nullptr);
        ln_kernel<<<1600, 256, 0, stream>>>(raw, out_b + l * 256, hf,
                                            ln1_g + l * 256, ln1_b + l * 256, out1f, out1bf);
        // FFN
        gemm_nt<EPI_RELU_BF><<<dim3(8, 50, 1), 256, 0, stream>>>(
            out1bf, f1wt + (long long)l * 1024 * 256, NBS, 1024, 256, 0, 0,
            nullptr, 0, ffn, ff1_b + l * 1024, nullptr, nullptr, nullptr, nullptr, nullptr);
        gemm_nt<EPI_F32><<<dim3(2, 50, 1), 256, 0, stream>>>(
            ffn, f2wt + (long long)l * 256 * 1024, NBS, 256, 1024, 0, 0,
            raw, 0, nullptr, nullptr, nullptr, nullptr, nullptr, nullptr, nullptr);
        ln_kernel<<<1600, 256, 0, stream>>>(raw, ff2_b + l * 256, out1f,
                                            ln2_g + l * 256, ln2_b + l * 256,
                                            (l == NL - 1) ? (float*)d_out : hf, hbf);
    }
}

// Round 3
// 1409.553 us; speedup vs baseline: 1.2324x; 1.2324x over previous
//
#include <hip/hip_runtime.h>
#include <hip/hip_bf16.h>

typedef __bf16 bf16x8 __attribute__((ext_vector_type(8)));
typedef float f32x4 __attribute__((ext_vector_type(4)));

#define NB 32
#define NS 200
#define SP 256
#define ND 256
#define NH 6
#define NL 8
#define NBS (NB*NS)      // 6400
#define NZ (NB*NH)       // 192
#define SLAB (SP*ND)     // 65536
#define PSTR 264         // P lds row stride (shorts)

using bf16 = __hip_bfloat16;

enum { EPI_F32 = 0, EPI_RELU_BF = 1, EPI_QKV = 2, EPI_ATOMIC = 3 };

__device__ __forceinline__ float b2f(bf16 x) { return __bfloat162float(x); }
__device__ __forceinline__ bf16 f2b(float x) { return __float2bfloat16(x); }
__device__ __forceinline__ unsigned short fbits(float x) { bf16 h = f2b(x); return *(unsigned short*)&h; }

// async global->LDS, 16B per lane. LDS dest must be wave-uniform base (HW adds lane*16).
__device__ __forceinline__ void gload16(const bf16* g, const short* l) {
    __builtin_amdgcn_global_load_lds(
        (const __attribute__((address_space(1))) unsigned int*)(unsigned long long)(g),
        (__attribute__((address_space(3))) unsigned int*)(unsigned long long)(l), 16, 0, 0);
}

// ---------------------------------------------------------------------------
// NT GEMM: C[m][n] = sum_k A[m][k]*B[n][k], A:[M,K] B:[N,K] bf16, K-major.
// 128x128 tile, 4 waves (2x2), mfma_16x16x32_bf16, global_load_lds staging,
// double-buffered 2-phase pipeline. blockIdx.z = split-K index (Kspan chunk).
// ---------------------------------------------------------------------------
template<int MODE>
__global__ __launch_bounds__(256)
void gemm_nt(const bf16* __restrict__ A, const bf16* __restrict__ Bm,
             int M, int N, int K, int Kspan,
             float* __restrict__ outF, bf16* __restrict__ outBf,
             const float* __restrict__ bias,
             const float* __restrict__ qkvb, const float* __restrict__ tnbp,
             bf16* __restrict__ Qb, bf16* __restrict__ Kb, bf16* __restrict__ Vb)
{
    __shared__ short Asl[2][128*32];
    __shared__ short Bsl[2][128*32];
    const int tid  = threadIdx.x;
    const int m0   = blockIdx.y * 128;
    const int n0   = blockIdx.x * 128;
    const int kbase= blockIdx.z * Kspan;
    const int lane = tid & 63, w = tid >> 6;
    const int wm   = (w >> 1) * 64, wn = (w & 1) * 64;
    const int fr   = lane & 15, kc = (lane >> 4) * 8;
    const int srow = lane >> 2, schk = (lane & 3) * 8;

    const bf16* Ag = A  + (long long)m0 * K + kbase;
    const bf16* Bg = Bm + (long long)n0 * K + kbase;

    f32x4 acc[4][4];
#pragma unroll
    for (int i = 0; i < 4; i++)
#pragma unroll
        for (int j = 0; j < 4; j++) acc[i][j] = (f32x4){0.f,0.f,0.f,0.f};

    auto stage = [&](int buf, int k0) {
        gload16(Ag + (long long)(w*32      + srow)*K + k0 + schk, &Asl[buf][(w*32     )*32]);
        gload16(Ag + (long long)(w*32 + 16 + srow)*K + k0 + schk, &Asl[buf][(w*32 + 16)*32]);
        gload16(Bg + (long long)(w*32      + srow)*K + k0 + schk, &Bsl[buf][(w*32     )*32]);
        gload16(Bg + (long long)(w*32 + 16 + srow)*K + k0 + schk, &Bsl[buf][(w*32 + 16)*32]);
    };

    stage(0, 0);
    __syncthreads();
    const int nt = Kspan >> 5;
    for (int t = 0; t < nt; t++) {
        const int buf = t & 1;
        if (t + 1 < nt) stage(buf ^ 1, (t+1)*32);
        bf16x8 af[4], bfm[4];
#pragma unroll
        for (int i = 0; i < 4; i++) af[i]  = *(const bf16x8*)&Asl[buf][(wm + i*16 + fr)*32 + kc];
#pragma unroll
        for (int j = 0; j < 4; j++) bfm[j] = *(const bf16x8*)&Bsl[buf][(wn + j*16 + fr)*32 + kc];
#pragma unroll
        for (int i = 0; i < 4; i++)
#pragma unroll
            for (int j = 0; j < 4; j++)
                acc[i][j] = __builtin_amdgcn_mfma_f32_16x16x32_bf16(af[i], bfm[j], acc[i][j], 0, 0, 0);
        __syncthreads();
    }

    const int rq = (lane >> 4) * 4;
#pragma unroll
    for (int i = 0; i < 4; i++) {
#pragma unroll
        for (int j = 0; j < 4; j++) {
            const int c  = n0 + wn + j*16 + fr;
            const int r0 = m0 + wm + i*16 + rq;
            if (MODE == EPI_F32) {
#pragma unroll
                for (int rg = 0; rg < 4; rg++)
                    outF[(long long)(r0+rg)*N + c] = acc[i][j][rg];
            } else if (MODE == EPI_ATOMIC) {
#pragma unroll
                for (int rg = 0; rg < 4; rg++)
                    atomicAdd(outF + (long long)(r0+rg)*N + c, acc[i][j][rg]);
            } else if (MODE == EPI_RELU_BF) {
                const float bv = bias[c];
#pragma unroll
                for (int rg = 0; rg < 4; rg++)
                    outBf[(long long)(r0+rg)*N + c] = f2b(fmaxf(acc[i][j][rg] + bv, 0.f));
            } else { // EPI_QKV
                const int x  = c / 1536;
                const int c1 = c - x*1536;
                const int hd = c1 >> 8, dd = c1 & 255;
                const float bv = (c1 < 512) ? qkvb[x*512 + c1] : tnbp[x*1024 + (c1 - 512)];
                if (x == 2) {
                    // V stored transposed: Vt[z][d][s]
                    const int bb = r0 / NS, ss0 = r0 - bb*NS;
                    if (ss0 <= NS - 4) {
                        ushort4 pk;
                        pk.x = fbits(acc[i][j][0] + bv);
                        pk.y = fbits(acc[i][j][1] + bv);
                        pk.z = fbits(acc[i][j][2] + bv);
                        pk.w = fbits(acc[i][j][3] + bv);
                        *(ushort4*)&Vb[((long long)((bb*NH + hd)*ND + dd))*SP + ss0] = pk;
                    } else {
#pragma unroll
                        for (int rg = 0; rg < 4; rg++) {
                            const int r = r0 + rg;
                            const int b2 = r / NS, s2 = r - b2*NS;
                            Vb[((long long)((b2*NH + hd)*ND + dd))*SP + s2] = f2b(acc[i][j][rg] + bv);
                        }
                    }
                } else {
                    bf16* dst = (x == 0) ? Qb : Kb;
#pragma unroll
                    for (int rg = 0; rg < 4; rg++) {
                        const int r = r0 + rg;
                        const int b2 = r / NS, s2 = r - b2*NS;
                        dst[((long long)((b2*NH + hd)*SP + s2))*ND + dd] = f2b(acc[i][j][rg] + bv);
                    }
                }
            }
        }
    }
}

// ---------------------------------------------------------------------------
// Fused attention: per block (z, 64-query quarter): S^T = K@Q^T -> softmax ->
// ctx = P@V. P staged through LDS. Vt is [z][d][s].
// ---------------------------------------------------------------------------
__global__ __launch_bounds__(256)
void attn_fused(const bf16* __restrict__ Qb, const bf16* __restrict__ Kb,
                const bf16* __restrict__ Vtb, const int* __restrict__ tokens,
                bf16* __restrict__ ctx)
{
    __shared__ __align__(16) char smem[16384 + 4096 + 1024 + 1024 + 64*PSTR*2];
    short* Ks    = (short*)smem;                        // [256][32], aliased by Vs in phase 2
    short* Qs    = (short*)(smem + 16384);              // [64][32]
    float* red   = (float*)(smem + 16384 + 4096);       // [256]
    float* maskv = (float*)(smem + 16384 + 4096 + 1024);// [256]
    short* P     = (short*)(smem + 16384 + 4096 + 2048);// [64][PSTR]

    const int z = blockIdx.y;
    const int b = z / NH, h = z - b*NH;
    const int q0 = blockIdx.x * 64;
    const int tid = threadIdx.x;
    const int lane = tid & 63, w = tid >> 6;
    const int fr = lane & 15, qh = lane >> 4;
    const int kc = qh * 8;
    const int srow = lane >> 2, schk = (lane & 3) * 8;

    const bf16* Kp = Kb  + (long long)z * SLAB;
    const bf16* Qp = Qb  + (long long)z * SLAB;
    const bf16* Vp = Vtb + (long long)z * SLAB;

    // key mask: -1e9 for pad tokens and for padded key slots
    {
        const int s = tid;
        float mv = -1e9f;
        if (s < NS && tokens[b*NS + s] != 0) mv = 0.f;
        maskv[s] = mv;
    }

    // ---- phase 1: S^T[s][q] = sum_d K[s,d] Q[q,d] ----
    f32x4 acc[4][4];
#pragma unroll
    for (int i = 0; i < 4; i++)
#pragma unroll
        for (int j = 0; j < 4; j++) acc[i][j] = (f32x4){0.f,0.f,0.f,0.f};

    for (int k0 = 0; k0 < ND; k0 += 32) {
#pragma unroll
        for (int r2 = 0; r2 < 4; r2++)
            gload16(Kp + (long long)(w*64 + r2*16 + srow)*ND + k0 + schk, &Ks[(w*64 + r2*16)*32]);
        gload16(Qp + (long long)(q0 + w*16 + srow)*ND + k0 + schk, &Qs[(w*16)*32]);
        __syncthreads();
        bf16x8 ak[4], bq[4];
#pragma unroll
        for (int i = 0; i < 4; i++) ak[i] = *(const bf16x8*)&Ks[(w*64 + i*16 + fr)*32 + kc];
#pragma unroll
        for (int j = 0; j < 4; j++) bq[j] = *(const bf16x8*)&Qs[(j*16 + fr)*32 + kc];
#pragma unroll
        for (int i = 0; i < 4; i++)
#pragma unroll
            for (int j = 0; j < 4; j++)
                acc[i][j] = __builtin_amdgcn_mfma_f32_16x16x32_bf16(ak[i], bq[j], acc[i][j], 0, 0, 0);
        __syncthreads();
    }

    // ---- softmax over s (rows of S^T) per column q ----
    // lane holds s = w*64 + i*16 + qh*4 + rg ; q = j*16 + fr
    float mk[4][4];
#pragma unroll
    for (int i = 0; i < 4; i++)
#pragma unroll
        for (int rg = 0; rg < 4; rg++) mk[i][rg] = maskv[w*64 + i*16 + qh*4 + rg];
#pragma unroll
    for (int i = 0; i < 4; i++)
#pragma unroll
        for (int j = 0; j < 4; j++)
#pragma unroll
            for (int rg = 0; rg < 4; rg++)
                acc[i][j][rg] = acc[i][j][rg] * 0.0625f + mk[i][rg];

    float pm[4];
#pragma unroll
    for (int j = 0; j < 4; j++) {
        float m = -3.0e38f;
#pragma unroll
        for (int i = 0; i < 4; i++)
#pragma unroll
            for (int rg = 0; rg < 4; rg++) m = fmaxf(m, acc[i][j][rg]);
        m = fmaxf(m, __shfl_xor(m, 16));
        m = fmaxf(m, __shfl_xor(m, 32));
        pm[j] = m;
    }
#pragma unroll
    for (int j = 0; j < 4; j++) red[w*64 + j*16 + fr] = pm[j];
    __syncthreads();
    float gm[4];
#pragma unroll
    for (int j = 0; j < 4; j++)
        gm[j] = fmaxf(fmaxf(red[j*16 + fr], red[64 + j*16 + fr]),
                      fmaxf(red[128 + j*16 + fr], red[192 + j*16 + fr]));
    float ps[4] = {0.f, 0.f, 0.f, 0.f};
#pragma unroll
    for (int i = 0; i < 4; i++)
#pragma unroll
        for (int j = 0; j < 4; j++)
#pragma unroll
            for (int rg = 0; rg < 4; rg++) {
                float e = __expf(acc[i][j][rg] - gm[j]);
                acc[i][j][rg] = e;
                ps[j] += e;
            }
#pragma unroll
    for (int j = 0; j < 4; j++) {
        ps[j] += __shfl_xor(ps[j], 16);
        ps[j] += __shfl_xor(ps[j], 32);
    }
    __syncthreads();
#pragma unroll
    for (int j = 0; j < 4; j++) red[w*64 + j*16 + fr] = ps[j];
    __syncthreads();
    float inv[4];
#pragma unroll
    for (int j = 0; j < 4; j++)
        inv[j] = 1.f / (red[j*16 + fr] + red[64 + j*16 + fr] + red[128 + j*16 + fr] + red[192 + j*16 + fr]);

    // write P[q][s] (bf16), rg-quads packed into 8B stores
#pragma unroll
    for (int i = 0; i < 4; i++)
#pragma unroll
        for (int j = 0; j < 4; j++) {
            ushort4 pk;
            pk.x = fbits(acc[i][j][0] * inv[j]);
            pk.y = fbits(acc[i][j][1] * inv[j]);
            pk.z = fbits(acc[i][j][2] * inv[j]);
            pk.w = fbits(acc[i][j][3] * inv[j]);
            *(ushort4*)&P[(j*16 + fr)*PSTR + w*64 + i*16 + qh*4] = pk;
        }

    // ---- phase 2: ctx[q][d] = sum_s P[q,s] Vt[d,s]; wave w owns d in [w*64, w*64+64) ----
    f32x4 acc2[4][4];
#pragma unroll
    for (int i = 0; i < 4; i++)
#pragma unroll
        for (int j = 0; j < 4; j++) acc2[i][j] = (f32x4){0.f,0.f,0.f,0.f};

    for (int s0 = 0; s0 < SP; s0 += 32) {
#pragma unroll
        for (int r2 = 0; r2 < 4; r2++)
            gload16(Vp + (long long)(w*64 + r2*16 + srow)*SP + s0 + schk, &Ks[(w*64 + r2*16)*32]);
        __syncthreads();
        bf16x8 ap[4], bv[4];
#pragma unroll
        for (int i = 0; i < 4; i++) ap[i] = *(const bf16x8*)&P[(i*16 + fr)*PSTR + s0 + kc];
#pragma unroll
        for (int j = 0; j < 4; j++) bv[j] = *(const bf16x8*)&Ks[(w*64 + j*16 + fr)*32 + kc];
#pragma unroll
        for (int i = 0; i < 4; i++)
#pragma unroll
            for (int j = 0; j < 4; j++)
                acc2[i][j] = __builtin_amdgcn_mfma_f32_16x16x32_bf16(ap[i], bv[j], acc2[i][j], 0, 0, 0);
        __syncthreads();
    }

#pragma unroll
    for (int i = 0; i < 4; i++)
#pragma unroll
        for (int j = 0; j < 4; j++)
#pragma unroll
            for (int rg = 0; rg < 4; rg++) {
                const int qg = q0 + i*16 + qh*4 + rg;
                if (qg < NS) {
                    const int d = w*64 + j*16 + fr;
                    ctx[((long long)(b*NS + qg))*1536 + h*256 + d] = f2b(acc2[i][j][rg]);
                }
            }
}

// ---------------------------------------------------------------------------
__global__ void embed_kernel(const int* __restrict__ tokens, const float* __restrict__ tok_emb,
                             const float* __restrict__ pos_emb, float* __restrict__ hf,
                             bf16* __restrict__ hbf)
{
    long long id = (long long)blockIdx.x * 256 + threadIdx.x;
    if (id >= (long long)NBS * ND) return;
    long long r = id >> 8;
    int j = id & 255;
    int tk = tokens[r];
    int s  = (int)(r % NS);
    float v = tok_emb[(long long)tk * ND + j] + pos_emb[s * ND + j];
    hf[id]  = v;
    hbf[id] = f2b(v);
}

__global__ void transpose_w(const float* __restrict__ in, bf16* __restrict__ out,
                            int L, int R, int C, long long total)
{
    long long id = (long long)blockIdx.x * 256 + threadIdx.x;
    if (id >= total) return;
    int l = (int)(id / ((long long)R * C));
    long long rem = id - (long long)l * R * C;
    int c = (int)(rem / R);
    int r = (int)(rem - (long long)c * R);
    out[id] = f2b(in[((long long)l * R + r) * C + c]);
}

__global__ void pack_cls(const float* __restrict__ wqkv, bf16* __restrict__ wcat)
{
    long long id = (long long)blockIdx.x * 256 + threadIdx.x;
    if (id >= 24ll * 512 * 256) return;
    int lx = (int)(id / (512 * 256));
    int rem = (int)(id - (long long)lx * 512 * 256);
    int n = rem >> 8;
    int k = rem & 255;
    wcat[((long long)lx * 1536 + n) * 256 + k] = f2b(wqkv[((long long)lx * 256 + k) * 512 + n]);
}

__global__ __launch_bounds__(256)
void build_wtns(const float* __restrict__ A1, const float* __restrict__ A2,
                const float* __restrict__ A3, const float* __restrict__ A4,
                bf16* __restrict__ wcat)
{
    int lx = blockIdx.x;
    __shared__ float a1s[32], a2s[128], a3s[128], a4s[32];
    int t = threadIdx.x;
    if (t < 32)  { a1s[t] = A1[lx*32 + t]; a4s[t] = A4[lx*32 + t]; }
    if (t < 128) { a2s[t] = A2[lx*128 + t]; a3s[t] = A3[lx*128 + t]; }
    __syncthreads();
    int d = t;
    int p = d >> 6, q = (d >> 4) & 3, rr = (d >> 2) & 3, tt = d & 3;
    for (int i = 0; i < 4; i++) {
        float w1_0 = a1s[(p*2 + 0)*4 + i];
        float w1_1 = a1s[(p*2 + 1)*4 + i];
        for (int j = 0; j < 8; j++) {
            float c1_0 = w1_0 * a2s[((q*2+0)*2+0)*8 + j] + w1_1 * a2s[((q*2+1)*2+0)*8 + j];
            float c1_1 = w1_0 * a2s[((q*2+0)*2+1)*8 + j] + w1_1 * a2s[((q*2+1)*2+1)*8 + j];
            for (int kk = 0; kk < 8; kk++) {
                float c2_0 = c1_0 * a3s[((rr*2+0)*2+0)*8 + kk] + c1_1 * a3s[((rr*2+1)*2+0)*8 + kk];
                float c2_1 = c1_0 * a3s[((rr*2+0)*2+1)*8 + kk] + c1_1 * a3s[((rr*2+1)*2+1)*8 + kk];
                for (int ll = 0; ll < 4; ll++) {
                    float sv = c2_0 * a4s[(tt*2 + 0)*4 + ll] + c2_1 * a4s[(tt*2 + 1)*4 + ll];
                    int e = ((i*8 + j)*8 + kk)*4 + ll;
                    wcat[((long long)lx * 1536 + 512 + e) * 256 + d] = f2b(sv);
                }
            }
        }
    }
}

__global__ __launch_bounds__(256)
void ln_kernel(const float* __restrict__ raw, const float* __restrict__ bias,
               const float* __restrict__ resid,
               const float* __restrict__ g, const float* __restrict__ bb,
               float* __restrict__ outF, bf16* __restrict__ outBf)
{
    int w = threadIdx.x >> 6, lane = threadIdx.x & 63;
    long long r = (long long)blockIdx.x * 4 + w;
    long long base = r * ND;
    float x[4]; float s = 0.f;
#pragma unroll
    for (int c = 0; c < 4; c++) {
        int j = lane + 64*c;
        x[c] = resid[base + j] + raw[base + j] + bias[j];
        s += x[c];
    }
#pragma unroll
    for (int o = 32; o; o >>= 1) s += __shfl_xor(s, o);
    float mean = s * (1.f/256.f);
    float vs = 0.f;
#pragma unroll
    for (int c = 0; c < 4; c++) { float d = x[c] - mean; vs += d*d; }
#pragma unroll
    for (int o = 32; o; o >>= 1) vs += __shfl_xor(vs, o);
    float rs = rsqrtf(vs * (1.f/256.f) + 1e-6f);
#pragma unroll
    for (int c = 0; c < 4; c++) {
        int j = lane + 64*c;
        float y = (x[c] - mean) * rs * g[j] + bb[j];
        outF[base + j]  = y;
        outBf[base + j] = f2b(y);
    }
}

// ---------------------------------------------------------------------------
extern "C" void kernel_launch(void* const* d_in, const int* in_sizes, int n_in,
                              void* d_out, int out_size, void* d_ws, size_t ws_size,
                              hipStream_t stream)
{
    const int*   tokens  = (const int*)  d_in[0];
    const float* tok_emb = (const float*)d_in[1];
    const float* pos_emb = (const float*)d_in[2];
    const float* wqkv_w  = (const float*)d_in[3];
    const float* wqkv_b  = (const float*)d_in[4];
    const float* A1      = (const float*)d_in[5];
    const float* A2      = (const float*)d_in[6];
    const float* A3      = (const float*)d_in[7];
    const float* A4      = (const float*)d_in[8];
    const float* tnb     = (const float*)d_in[9];
    const float* out_w   = (const float*)d_in[10];
    const float* out_b   = (const float*)d_in[11];
    const float* ff1_w   = (const float*)d_in[12];
    const float* ff1_b   = (const float*)d_in[13];
    const float* ff2_w   = (const float*)d_in[14];
    const float* ff2_b   = (const float*)d_in[15];
    const float* ln1_g   = (const float*)d_in[16];
    const float* ln1_b   = (const float*)d_in[17];
    const float* ln2_g   = (const float*)d_in[18];
    const float* ln2_b   = (const float*)d_in[19];

    char* ws = (char*)d_ws;
    size_t off = 0;
    auto alloc = [&](size_t bytes) -> char* {
        char* p = ws + off;
        off += (bytes + 255) & ~(size_t)255;
        return p;
    };
    float* hf    = (float*)alloc((size_t)NBS * ND * 4);
    bf16*  hbf   = (bf16*) alloc((size_t)NBS * ND * 2);
    bf16*  wcat  = (bf16*) alloc(24ull * 1536 * 256 * 2);
    bf16*  owt   = (bf16*) alloc(8ull * 256 * 1536 * 2);
    bf16*  f1wt  = (bf16*) alloc(8ull * 1024 * 256 * 2);
    bf16*  f2wt  = (bf16*) alloc(8ull * 256 * 1024 * 2);
    bf16*  Qb    = (bf16*) alloc((size_t)NZ * SLAB * 2);
    bf16*  Kb    = (bf16*) alloc((size_t)NZ * SLAB * 2);
    bf16*  Vtb   = (bf16*) alloc((size_t)NZ * SLAB * 2);
    bf16*  ctxg  = (bf16*) alloc((size_t)NBS * 1536 * 2);
    bf16*  ffn   = (bf16*) alloc((size_t)NBS * 1024 * 2);
    float* raw   = (float*)alloc((size_t)NBS * ND * 4);
    float* out1f = (float*)alloc((size_t)NBS * ND * 4);
    bf16*  out1bf= (bf16*) alloc((size_t)NBS * ND * 2);
    if (off > ws_size) return;

    // zero Q/K/Vt so padded rows/cols are exactly 0 (pad never rewritten per layer)
    hipMemsetAsync(Qb,  0, (size_t)NZ * SLAB * 2, stream);
    hipMemsetAsync(Kb,  0, (size_t)NZ * SLAB * 2, stream);
    hipMemsetAsync(Vtb, 0, (size_t)NZ * SLAB * 2, stream);

    embed_kernel<<<NBS, 256, 0, stream>>>(tokens, tok_emb, pos_emb, hf, hbf);
    pack_cls<<<12288, 256, 0, stream>>>(wqkv_w, wcat);
    build_wtns<<<24, 256, 0, stream>>>(A1, A2, A3, A4, wcat);
    transpose_w<<<12288, 256, 0, stream>>>(out_w, owt, 8, 1536, 256, 8ll*1536*256);
    transpose_w<<<8192, 256, 0, stream>>>(ff1_w, f1wt, 8, 256, 1024, 8ll*256*1024);
    transpose_w<<<8192, 256, 0, stream>>>(ff2_w, f2wt, 8, 1024, 256, 8ll*1024*256);

    for (int l = 0; l < NL; l++) {
        // QKV (cls + tensor heads): [6400,256] @ [4608,256]^T, scatter epilogue
        gemm_nt<EPI_QKV><<<dim3(36, 50, 1), 256, 0, stream>>>(
            hbf, wcat + (long long)l * 3 * 1536 * 256, NBS, 4608, 256, 256,
            nullptr, nullptr, nullptr,
            wqkv_b + l * 3 * 512, tnb + l * 3 * 1024, Qb, Kb, Vtb);
        // fused attention -> ctxg [6400][1536]
        attn_fused<<<dim3(4, NZ), 256, 0, stream>>>(Qb, Kb, Vtb, tokens, ctxg);
        // out projection, split-K=3 with atomics
        hipMemsetAsync(raw, 0, (size_t)NBS * ND * 4, stream);
        gemm_nt<EPI_ATOMIC><<<dim3(2, 50, 3), 256, 0, stream>>>(
            ctxg, owt + (long long)l * 256 * 1536, NBS, 256, 1536, 512,
            raw, nullptr, nullptr, nullptr, nullptr, nullptr, nullptr, nullptr);
        ln_kernel<<<1600, 256, 0, stream>>>(raw, out_b + l * 256, hf,
                                            ln1_g + l * 256, ln1_b + l * 256, out1f, out1bf);
        // FFN
        gemm_nt<EPI_RELU_BF><<<dim3(8, 50, 1), 256, 0, stream>>>(
            out1bf, f1wt + (long long)l * 1024 * 256, NBS, 1024, 256, 256,
            nullptr, ffn, ff1_b + l * 1024, nullptr, nullptr, nullptr, nullptr, nullptr);
        hipMemsetAsync(raw, 0, (size_t)NBS * ND * 4, stream);
        gemm_nt<EPI_ATOMIC><<<dim3(2, 50, 4), 256, 0, stream>>>(
            ffn, f2wt + (long long)l * 256 * 1024, NBS, 256, 1024, 256,
            raw, nullptr, nullptr, nullptr, nullptr, nullptr, nullptr, nullptr);
        ln_kernel<<<1600, 256, 0, stream>>>(raw, ff2_b + l * 256, out1f,
                                            ln2_g + l * 256, ln2_b + l * 256,
                                            (l == NL - 1) ? (float*)d_out : hf, hbf);
    }
}

// Round 4
// 1146.608 us; speedup vs baseline: 1.5150x; 1.2293x over previous
//
#include <hip/hip_runtime.h>
#include <hip/hip_bf16.h>

typedef __bf16 bf16x8 __attribute__((ext_vector_type(8)));
typedef float f32x4 __attribute__((ext_vector_type(4)));

#define NB 32
#define NS 200
#define SP 256
#define ND 256
#define NH 6
#define NL 8
#define NBS (NB*NS)      // 6400
#define NZ (NB*NH)       // 192
#define SLAB (SP*ND)     // 65536
#define PSTR 264         // P lds row stride (shorts)

using bf16 = __hip_bfloat16;

enum { EPI_F32 = 0, EPI_RELU_BF = 1, EPI_QKV = 2, EPI_VT = 3 };

__device__ __forceinline__ float b2f(bf16 x) { return __bfloat162float(x); }
__device__ __forceinline__ bf16 f2b(float x) { return __float2bfloat16(x); }
__device__ __forceinline__ unsigned short fbits(float x) { bf16 h = f2b(x); return *(unsigned short*)&h; }

// async global->LDS, 16B per lane. LDS dest must be wave-uniform base (HW adds lane*16).
__device__ __forceinline__ void gload16(const bf16* g, const short* l) {
    __builtin_amdgcn_global_load_lds(
        (const __attribute__((address_space(1))) unsigned int*)(unsigned long long)(g),
        (__attribute__((address_space(3))) unsigned int*)(unsigned long long)(l), 16, 0, 0);
}

// ---------------------------------------------------------------------------
// NT GEMM: C[m][n] = sum_k A[m][k]*B[n][k], A:[M,K] B:[N,K] bf16, K-major.
// 128x128 tile, 4 waves (2x2), mfma_16x16x32_bf16.
// T3/T4: 3 LDS buffers, prefetch depth 2, counted vmcnt (8/4/0), raw barriers.
// blockIdx.z = split-K chunk; EPI_F32 writes partial to outF + z*sOz.
// ---------------------------------------------------------------------------
template<int MODE>
__global__ __launch_bounds__(256)
void gemm_nt(const bf16* __restrict__ A, const bf16* __restrict__ Bm,
             int M, int N, int K, int Kspan, long long sOz,
             float* __restrict__ outF, bf16* __restrict__ outBf,
             const float* __restrict__ bias,
             const float* __restrict__ qkvb, const float* __restrict__ tnbp,
             bf16* __restrict__ Qb, bf16* __restrict__ Kb, bf16* __restrict__ Vb)
{
    __shared__ short Asl[3][128*32];
    __shared__ short Bsl[3][128*32];
    const int tid  = threadIdx.x;
    const int m0   = blockIdx.y * 128;
    const int n0   = blockIdx.x * 128;
    const int kbase= blockIdx.z * Kspan;
    const int lane = tid & 63, w = tid >> 6;
    const int wm   = (w >> 1) * 64, wn = (w & 1) * 64;
    const int fr   = lane & 15, kc = (lane >> 4) * 8;
    const int srow = lane >> 2, schk = (lane & 3) * 8;

    const bf16* Ag = A  + (long long)m0 * K + kbase;
    const bf16* Bg = Bm + (long long)n0 * K + kbase;

    f32x4 acc[4][4];
#pragma unroll
    for (int i = 0; i < 4; i++)
#pragma unroll
        for (int j = 0; j < 4; j++) acc[i][j] = (f32x4){0.f,0.f,0.f,0.f};

    auto stage = [&](int buf, int k0) {
        gload16(Ag + (long long)(w*32      + srow)*K + k0 + schk, &Asl[buf][(w*32     )*32]);
        gload16(Ag + (long long)(w*32 + 16 + srow)*K + k0 + schk, &Asl[buf][(w*32 + 16)*32]);
        gload16(Bg + (long long)(w*32      + srow)*K + k0 + schk, &Bsl[buf][(w*32     )*32]);
        gload16(Bg + (long long)(w*32 + 16 + srow)*K + k0 + schk, &Bsl[buf][(w*32 + 16)*32]);
    };

    const int nt = Kspan >> 5;
    stage(0, 0);
    stage(1, 32);
    for (int t = 0; t < nt; t++) {
        const int buf = t % 3;
        if (t + 2 < nt) {
            stage((t + 2) % 3, (t + 2) * 32);
            asm volatile("s_waitcnt vmcnt(8)" ::: "memory");   // oldest 4 (tile t) landed
        } else if (t + 1 < nt) {
            asm volatile("s_waitcnt vmcnt(4)" ::: "memory");
        } else {
            asm volatile("s_waitcnt vmcnt(0)" ::: "memory");
        }
        __builtin_amdgcn_s_barrier();                           // all waves' t-loads landed
        __builtin_amdgcn_sched_barrier(0);
        bf16x8 af[4], bfm[4];
#pragma unroll
        for (int i = 0; i < 4; i++) af[i]  = *(const bf16x8*)&Asl[buf][(wm + i*16 + fr)*32 + kc];
#pragma unroll
        for (int j = 0; j < 4; j++) bfm[j] = *(const bf16x8*)&Bsl[buf][(wn + j*16 + fr)*32 + kc];
#pragma unroll
        for (int i = 0; i < 4; i++)
#pragma unroll
            for (int j = 0; j < 4; j++)
                acc[i][j] = __builtin_amdgcn_mfma_f32_16x16x32_bf16(af[i], bfm[j], acc[i][j], 0, 0, 0);
        __builtin_amdgcn_s_barrier();                           // protect buf before re-stage
        __builtin_amdgcn_sched_barrier(0);
    }

    const int rq = (lane >> 4) * 4;
#pragma unroll
    for (int i = 0; i < 4; i++) {
        const int r0 = m0 + wm + i*16 + rq;
        // row-dependent precompute
        int b2r = 0, s20 = 0, hdV = 0, dd0 = 0;
        float bvv[4];
        if (MODE == EPI_QKV) { b2r = r0 / NS; s20 = r0 - b2r*NS; }
        if (MODE == EPI_VT) {
            hdV = r0 >> 8; dd0 = r0 & 255;
#pragma unroll
            for (int rg = 0; rg < 4; rg++) {
                const int rr = r0 + rg;
                bvv[rg] = (rr < 512) ? qkvb[1024 + rr] : tnbp[2048 + rr - 512];
            }
        }
#pragma unroll
        for (int j = 0; j < 4; j++) {
            const int c = n0 + wn + j*16 + fr;
            if (MODE == EPI_F32) {
#pragma unroll
                for (int rg = 0; rg < 4; rg++)
                    outF[(long long)blockIdx.z * sOz + (long long)(r0+rg)*N + c] = acc[i][j][rg];
            } else if (MODE == EPI_RELU_BF) {
                const float bv = bias[c];
#pragma unroll
                for (int rg = 0; rg < 4; rg++)
                    outBf[(long long)(r0+rg)*N + c] = f2b(fmaxf(acc[i][j][rg] + bv, 0.f));
            } else if (MODE == EPI_QKV) {
                const int x  = (c >= 1536);
                const int c1 = c - x*1536;
                const int hd = c1 >> 8, dd = c1 & 255;
                const float bv = (c1 < 512) ? qkvb[x*512 + c1] : tnbp[x*1024 + (c1 - 512)];
                bf16* dst = x ? Kb : Qb;
#pragma unroll
                for (int rg = 0; rg < 4; rg++) {
                    int bb = b2r, ss = s20 + rg;
                    if (ss >= NS) { bb++; ss -= NS; }
                    dst[((long long)((bb*NH + hd)*SP + ss))*ND + dd] = f2b(acc[i][j][rg] + bv);
                }
            } else { // EPI_VT: rows = V output dim, cols = tokens; Vt[z][d][s]
                const int b2 = c / NS;
                const int s2 = c - b2*NS;
                const long long base = ((long long)((b2*NH + hdV)*ND + dd0))*SP + s2;
#pragma unroll
                for (int rg = 0; rg < 4; rg++)
                    Vb[base + (long long)rg*SP] = f2b(acc[i][j][rg] + bvv[rg]);
            }
        }
    }
}

// ---------------------------------------------------------------------------
// Fused attention: per block (z, 64-query quarter): S^T = K@Q^T -> softmax ->
// ctx = P@V. P staged through LDS. Vt is [z][d][s].
// ---------------------------------------------------------------------------
__global__ __launch_bounds__(256)
void attn_fused(const bf16* __restrict__ Qb, const bf16* __restrict__ Kb,
                const bf16* __restrict__ Vtb, const int* __restrict__ tokens,
                bf16* __restrict__ ctx)
{
    __shared__ __align__(16) char smem[16384 + 4096 + 1024 + 1024 + 64*PSTR*2];
    short* Ks    = (short*)smem;                        // [256][32], aliased by Vs in phase 2
    short* Qs    = (short*)(smem + 16384);              // [64][32]
    float* red   = (float*)(smem + 16384 + 4096);       // [256]
    float* maskv = (float*)(smem + 16384 + 4096 + 1024);// [256]
    short* P     = (short*)(smem + 16384 + 4096 + 2048);// [64][PSTR]

    const int z = blockIdx.y;
    const int b = z / NH, h = z - b*NH;
    const int q0 = blockIdx.x * 64;
    const int tid = threadIdx.x;
    const int lane = tid & 63, w = tid >> 6;
    const int fr = lane & 15, qh = lane >> 4;
    const int kc = qh * 8;
    const int srow = lane >> 2, schk = (lane & 3) * 8;

    const bf16* Kp = Kb  + (long long)z * SLAB;
    const bf16* Qp = Qb  + (long long)z * SLAB;
    const bf16* Vp = Vtb + (long long)z * SLAB;

    {
        const int s = tid;
        float mv = -1e9f;
        if (s < NS && tokens[b*NS + s] != 0) mv = 0.f;
        maskv[s] = mv;
    }

    // ---- phase 1: S^T[s][q] = sum_d K[s,d] Q[q,d] ----
    f32x4 acc[4][4];
#pragma unroll
    for (int i = 0; i < 4; i++)
#pragma unroll
        for (int j = 0; j < 4; j++) acc[i][j] = (f32x4){0.f,0.f,0.f,0.f};

    for (int k0 = 0; k0 < ND; k0 += 32) {
#pragma unroll
        for (int r2 = 0; r2 < 4; r2++)
            gload16(Kp + (long long)(w*64 + r2*16 + srow)*ND + k0 + schk, &Ks[(w*64 + r2*16)*32]);
        gload16(Qp + (long long)(q0 + w*16 + srow)*ND + k0 + schk, &Qs[(w*16)*32]);
        __syncthreads();
        bf16x8 ak[4], bq[4];
#pragma unroll
        for (int i = 0; i < 4; i++) ak[i] = *(const bf16x8*)&Ks[(w*64 + i*16 + fr)*32 + kc];
#pragma unroll
        for (int j = 0; j < 4; j++) bq[j] = *(const bf16x8*)&Qs[(j*16 + fr)*32 + kc];
#pragma unroll
        for (int i = 0; i < 4; i++)
#pragma unroll
            for (int j = 0; j < 4; j++)
                acc[i][j] = __builtin_amdgcn_mfma_f32_16x16x32_bf16(ak[i], bq[j], acc[i][j], 0, 0, 0);
        __syncthreads();
    }

    // ---- softmax over s per column q ----
    float mk[4][4];
#pragma unroll
    for (int i = 0; i < 4; i++)
#pragma unroll
        for (int rg = 0; rg < 4; rg++) mk[i][rg] = maskv[w*64 + i*16 + qh*4 + rg];
#pragma unroll
    for (int i = 0; i < 4; i++)
#pragma unroll
        for (int j = 0; j < 4; j++)
#pragma unroll
            for (int rg = 0; rg < 4; rg++)
                acc[i][j][rg] = acc[i][j][rg] * 0.0625f + mk[i][rg];

    float pm[4];
#pragma unroll
    for (int j = 0; j < 4; j++) {
        float m = -3.0e38f;
#pragma unroll
        for (int i = 0; i < 4; i++)
#pragma unroll
            for (int rg = 0; rg < 4; rg++) m = fmaxf(m, acc[i][j][rg]);
        m = fmaxf(m, __shfl_xor(m, 16));
        m = fmaxf(m, __shfl_xor(m, 32));
        pm[j] = m;
    }
#pragma unroll
    for (int j = 0; j < 4; j++) red[w*64 + j*16 + fr] = pm[j];
    __syncthreads();
    float gm[4];
#pragma unroll
    for (int j = 0; j < 4; j++)
        gm[j] = fmaxf(fmaxf(red[j*16 + fr], red[64 + j*16 + fr]),
                      fmaxf(red[128 + j*16 + fr], red[192 + j*16 + fr]));
    float ps[4] = {0.f, 0.f, 0.f, 0.f};
#pragma unroll
    for (int i = 0; i < 4; i++)
#pragma unroll
        for (int j = 0; j < 4; j++)
#pragma unroll
            for (int rg = 0; rg < 4; rg++) {
                float e = __expf(acc[i][j][rg] - gm[j]);
                acc[i][j][rg] = e;
                ps[j] += e;
            }
#pragma unroll
    for (int j = 0; j < 4; j++) {
        ps[j] += __shfl_xor(ps[j], 16);
        ps[j] += __shfl_xor(ps[j], 32);
    }
    __syncthreads();
#pragma unroll
    for (int j = 0; j < 4; j++) red[w*64 + j*16 + fr] = ps[j];
    __syncthreads();
    float inv[4];
#pragma unroll
    for (int j = 0; j < 4; j++)
        inv[j] = 1.f / (red[j*16 + fr] + red[64 + j*16 + fr] + red[128 + j*16 + fr] + red[192 + j*16 + fr]);

#pragma unroll
    for (int i = 0; i < 4; i++)
#pragma unroll
        for (int j = 0; j < 4; j++) {
            ushort4 pk;
            pk.x = fbits(acc[i][j][0] * inv[j]);
            pk.y = fbits(acc[i][j][1] * inv[j]);
            pk.z = fbits(acc[i][j][2] * inv[j]);
            pk.w = fbits(acc[i][j][3] * inv[j]);
            *(ushort4*)&P[(j*16 + fr)*PSTR + w*64 + i*16 + qh*4] = pk;
        }

    // ---- phase 2: ctx[q][d] = sum_s P[q,s] Vt[d,s], s < 224 (P==0 beyond) ----
    f32x4 acc2[4][4];
#pragma unroll
    for (int i = 0; i < 4; i++)
#pragma unroll
        for (int j = 0; j < 4; j++) acc2[i][j] = (f32x4){0.f,0.f,0.f,0.f};

    for (int s0 = 0; s0 < 224; s0 += 32) {
#pragma unroll
        for (int r2 = 0; r2 < 4; r2++)
            gload16(Vp + (long long)(w*64 + r2*16 + srow)*SP + s0 + schk, &Ks[(w*64 + r2*16)*32]);
        __syncthreads();
        bf16x8 ap[4], bv[4];
#pragma unroll
        for (int i = 0; i < 4; i++) ap[i] = *(const bf16x8*)&P[(i*16 + fr)*PSTR + s0 + kc];
#pragma unroll
        for (int j = 0; j < 4; j++) bv[j] = *(const bf16x8*)&Ks[(w*64 + j*16 + fr)*32 + kc];
#pragma unroll
        for (int i = 0; i < 4; i++)
#pragma unroll
            for (int j = 0; j < 4; j++)
                acc2[i][j] = __builtin_amdgcn_mfma_f32_16x16x32_bf16(ap[i], bv[j], acc2[i][j], 0, 0, 0);
        __syncthreads();
    }

#pragma unroll
    for (int i = 0; i < 4; i++)
#pragma unroll
        for (int j = 0; j < 4; j++)
#pragma unroll
            for (int rg = 0; rg < 4; rg++) {
                const int qg = q0 + i*16 + qh*4 + rg;
                if (qg < NS) {
                    const int d = w*64 + j*16 + fr;
                    ctx[((long long)(b*NS + qg))*1536 + h*256 + d] = f2b(acc2[i][j][rg]);
                }
            }
}

// ---------------------------------------------------------------------------
__global__ void embed_kernel(const int* __restrict__ tokens, const float* __restrict__ tok_emb,
                             const float* __restrict__ pos_emb, float* __restrict__ hf,
                             bf16* __restrict__ hbf)
{
    long long id = (long long)blockIdx.x * 256 + threadIdx.x;
    if (id >= (long long)NBS * ND) return;
    long long r = id >> 8;
    int j = id & 255;
    int tk = tokens[r];
    int s  = (int)(r % NS);
    float v = tok_emb[(long long)tk * ND + j] + pos_emb[s * ND + j];
    hf[id]  = v;
    hbf[id] = f2b(v);
}

__global__ void transpose_w(const float* __restrict__ in, bf16* __restrict__ out,
                            int L, int R, int C, long long total)
{
    long long id = (long long)blockIdx.x * 256 + threadIdx.x;
    if (id >= total) return;
    int l = (int)(id / ((long long)R * C));
    long long rem = id - (long long)l * R * C;
    int c = (int)(rem / R);
    int r = (int)(rem - (long long)c * R);
    out[id] = f2b(in[((long long)l * R + r) * C + c]);
}

__global__ void pack_cls(const float* __restrict__ wqkv, bf16* __restrict__ wcat)
{
    long long id = (long long)blockIdx.x * 256 + threadIdx.x;
    if (id >= 24ll * 512 * 256) return;
    int lx = (int)(id / (512 * 256));
    int rem = (int)(id - (long long)lx * 512 * 256);
    int n = rem >> 8;
    int k = rem & 255;
    wcat[((long long)lx * 1536 + n) * 256 + k] = f2b(wqkv[((long long)lx * 256 + k) * 512 + n]);
}

__global__ __launch_bounds__(256)
void build_wtns(const float* __restrict__ A1, const float* __restrict__ A2,
                const float* __restrict__ A3, const float* __restrict__ A4,
                bf16* __restrict__ wcat)
{
    int lx = blockIdx.x;
    __shared__ float a1s[32], a2s[128], a3s[128], a4s[32];
    int t = threadIdx.x;
    if (t < 32)  { a1s[t] = A1[lx*32 + t]; a4s[t] = A4[lx*32 + t]; }
    if (t < 128) { a2s[t] = A2[lx*128 + t]; a3s[t] = A3[lx*128 + t]; }
    __syncthreads();
    int d = t;
    int p = d >> 6, q = (d >> 4) & 3, rr = (d >> 2) & 3, tt = d & 3;
    for (int i = 0; i < 4; i++) {
        float w1_0 = a1s[(p*2 + 0)*4 + i];
        float w1_1 = a1s[(p*2 + 1)*4 + i];
        for (int j = 0; j < 8; j++) {
            float c1_0 = w1_0 * a2s[((q*2+0)*2+0)*8 + j] + w1_1 * a2s[((q*2+1)*2+0)*8 + j];
            float c1_1 = w1_0 * a2s[((q*2+0)*2+1)*8 + j] + w1_1 * a2s[((q*2+1)*2+1)*8 + j];
            for (int kk = 0; kk < 8; kk++) {
                float c2_0 = c1_0 * a3s[((rr*2+0)*2+0)*8 + kk] + c1_1 * a3s[((rr*2+1)*2+0)*8 + kk];
                float c2_1 = c1_0 * a3s[((rr*2+0)*2+1)*8 + kk] + c1_1 * a3s[((rr*2+1)*2+1)*8 + kk];
                for (int ll = 0; ll < 4; ll++) {
                    float sv = c2_0 * a4s[(tt*2 + 0)*4 + ll] + c2_1 * a4s[(tt*2 + 1)*4 + ll];
                    int e = ((i*8 + j)*8 + kk)*4 + ll;
                    wcat[((long long)lx * 1536 + 512 + e) * 256 + d] = f2b(sv);
                }
            }
        }
    }
}

// out = LN(resid + raw0 + raw1 + bias) * g + b
__global__ __launch_bounds__(256)
void ln_kernel(const float* __restrict__ raw0, const float* __restrict__ raw1,
               const float* __restrict__ bias, const float* __restrict__ resid,
               const float* __restrict__ g, const float* __restrict__ bb,
               float* __restrict__ outF, bf16* __restrict__ outBf)
{
    int w = threadIdx.x >> 6, lane = threadIdx.x & 63;
    long long r = (long long)blockIdx.x * 4 + w;
    long long base = r * ND;
    float x[4]; float s = 0.f;
#pragma unroll
    for (int c = 0; c < 4; c++) {
        int j = lane + 64*c;
        x[c] = resid[base + j] + raw0[base + j] + raw1[base + j] + bias[j];
        s += x[c];
    }
#pragma unroll
    for (int o = 32; o; o >>= 1) s += __shfl_xor(s, o);
    float mean = s * (1.f/256.f);
    float vs = 0.f;
#pragma unroll
    for (int c = 0; c < 4; c++) { float d = x[c] - mean; vs += d*d; }
#pragma unroll
    for (int o = 32; o; o >>= 1) vs += __shfl_xor(vs, o);
    float rs = rsqrtf(vs * (1.f/256.f) + 1e-6f);
#pragma unroll
    for (int c = 0; c < 4; c++) {
        int j = lane + 64*c;
        float y = (x[c] - mean) * rs * g[j] + bb[j];
        outF[base + j]  = y;
        outBf[base + j] = f2b(y);
    }
}

// ---------------------------------------------------------------------------
extern "C" void kernel_launch(void* const* d_in, const int* in_sizes, int n_in,
                              void* d_out, int out_size, void* d_ws, size_t ws_size,
                              hipStream_t stream)
{
    const int*   tokens  = (const int*)  d_in[0];
    const float* tok_emb = (const float*)d_in[1];
    const float* pos_emb = (const float*)d_in[2];
    const float* wqkv_w  = (const float*)d_in[3];
    const float* wqkv_b  = (const float*)d_in[4];
    const float* A1      = (const float*)d_in[5];
    const float* A2      = (const float*)d_in[6];
    const float* A3      = (const float*)d_in[7];
    const float* A4      = (const float*)d_in[8];
    const float* tnb     = (const float*)d_in[9];
    const float* out_w   = (const float*)d_in[10];
    const float* out_b   = (const float*)d_in[11];
    const float* ff1_w   = (const float*)d_in[12];
    const float* ff1_b   = (const float*)d_in[13];
    const float* ff2_w   = (const float*)d_in[14];
    const float* ff2_b   = (const float*)d_in[15];
    const float* ln1_g   = (const float*)d_in[16];
    const float* ln1_b   = (const float*)d_in[17];
    const float* ln2_g   = (const float*)d_in[18];
    const float* ln2_b   = (const float*)d_in[19];

    char* ws = (char*)d_ws;
    size_t off = 0;
    auto alloc = [&](size_t bytes) -> char* {
        char* p = ws + off;
        off += (bytes + 255) & ~(size_t)255;
        return p;
    };
    float* hf    = (float*)alloc((size_t)NBS * ND * 4);
    bf16*  hbf   = (bf16*) alloc((size_t)NBS * ND * 2);
    bf16*  wcat  = (bf16*) alloc(24ull * 1536 * 256 * 2);
    bf16*  owt   = (bf16*) alloc(8ull * 256 * 1536 * 2);
    bf16*  f1wt  = (bf16*) alloc(8ull * 1024 * 256 * 2);
    bf16*  f2wt  = (bf16*) alloc(8ull * 256 * 1024 * 2);
    bf16*  Qb    = (bf16*) alloc((size_t)NZ * SLAB * 2);
    bf16*  Kb    = (bf16*) alloc((size_t)NZ * SLAB * 2);
    bf16*  Vtb   = (bf16*) alloc((size_t)NZ * SLAB * 2);
    bf16*  ctxg  = (bf16*) alloc((size_t)NBS * 1536 * 2);
    bf16*  ffn   = (bf16*) alloc((size_t)NBS * 1024 * 2);
    float* raw   = (float*)alloc((size_t)NBS * ND * 4 * 2);   // 2 split-K partials
    float* out1f = (float*)alloc((size_t)NBS * ND * 4);
    bf16*  out1bf= (bf16*) alloc((size_t)NBS * ND * 2);
    if (off > ws_size) return;
    float* raw1 = raw + (size_t)NBS * ND;

    // zero Q/K/Vt pads once (pad rows/cols never rewritten)
    hipMemsetAsync(Qb,  0, (size_t)NZ * SLAB * 2, stream);
    hipMemsetAsync(Kb,  0, (size_t)NZ * SLAB * 2, stream);
    hipMemsetAsync(Vtb, 0, (size_t)NZ * SLAB * 2, stream);

    embed_kernel<<<NBS, 256, 0, stream>>>(tokens, tok_emb, pos_emb, hf, hbf);
    pack_cls<<<12288, 256, 0, stream>>>(wqkv_w, wcat);
    build_wtns<<<24, 256, 0, stream>>>(A1, A2, A3, A4, wcat);
    transpose_w<<<12288, 256, 0, stream>>>(out_w, owt, 8, 1536, 256, 8ll*1536*256);
    transpose_w<<<8192, 256, 0, stream>>>(ff1_w, f1wt, 8, 256, 1024, 8ll*256*1024);
    transpose_w<<<8192, 256, 0, stream>>>(ff2_w, f2wt, 8, 1024, 256, 8ll*1024*256);

    for (int l = 0; l < NL; l++) {
        const bf16* wl = wcat + (long long)l * 3 * 1536 * 256;
        // Q,K projection: [6400,256] @ [3072,256]^T -> Q/K slabs [z][s][d]
        gemm_nt<EPI_QKV><<<dim3(24, 50, 1), 256, 0, stream>>>(
            hbf, wl, NBS, 3072, 256, 256, 0, nullptr, nullptr, nullptr,
            wqkv_b + l * 3 * 512, tnb + l * 3 * 1024, Qb, Kb, nullptr);
        // V^T projection: [1536,256] @ [6400,256]^T -> Vt [z][d][s]
        gemm_nt<EPI_VT><<<dim3(50, 12, 1), 256, 0, stream>>>(
            wl + 2ll * 1536 * 256, hbf, 1536, NBS, 256, 256, 0, nullptr, nullptr, nullptr,
            wqkv_b + l * 3 * 512, tnb + l * 3 * 1024, nullptr, nullptr, Vtb);
        // fused attention -> ctxg [6400][1536]
        attn_fused<<<dim3(4, NZ), 256, 0, stream>>>(Qb, Kb, Vtb, tokens, ctxg);
        // out projection, split-K=2 partials (no atomics)
        gemm_nt<EPI_F32><<<dim3(2, 50, 2), 256, 0, stream>>>(
            ctxg, owt + (long long)l * 256 * 1536, NBS, 256, 1536, 768, (long long)NBS*ND,
            raw, nullptr, nullptr, nullptr, nullptr, nullptr, nullptr, nullptr);
        ln_kernel<<<1600, 256, 0, stream>>>(raw, raw1, out_b + l * 256, hf,
                                            ln1_g + l * 256, ln1_b + l * 256, out1f, out1bf);
        // FFN
        gemm_nt<EPI_RELU_BF><<<dim3(8, 50, 1), 256, 0, stream>>>(
            out1bf, f1wt + (long long)l * 1024 * 256, NBS, 1024, 256, 256, 0,
            nullptr, ffn, ff1_b + l * 1024, nullptr, nullptr, nullptr, nullptr, nullptr);
        gemm_nt<EPI_F32><<<dim3(2, 50, 2), 256, 0, stream>>>(
            ffn, f2wt + (long long)l * 256 * 1024, NBS, 256, 1024, 512, (long long)NBS*ND,
            raw, nullptr, nullptr, nullptr, nullptr, nullptr, nullptr, nullptr);
        ln_kernel<<<1600, 256, 0, stream>>>(raw, raw1, ff2_b + l * 256, out1f,
                                            ln2_g + l * 256, ln2_b + l * 256,
                                            (l == NL - 1) ? (float*)d_out : hf, hbf);
    }
}

// Round 5
// 1045.651 us; speedup vs baseline: 1.6613x; 1.0965x over previous
//
#include <hip/hip_runtime.h>
#include <hip/hip_bf16.h>

typedef __bf16 bf16x8 __attribute__((ext_vector_type(8)));
typedef float f32x4 __attribute__((ext_vector_type(4)));

#define NB 32
#define NS 200
#define SP 256
#define ND 256
#define NH 6
#define NL 8
#define NBS (NB*NS)      // 6400
#define NZ (NB*NH)       // 192
#define SLAB (SP*ND)     // 65536
#define PSTR 264         // P lds row stride (shorts)

using bf16 = __hip_bfloat16;

enum { EPI_F32 = 0, EPI_RELU_BF = 1, EPI_QKV = 2, EPI_VT = 3 };

__device__ __forceinline__ float b2f(bf16 x) { return __bfloat162float(x); }
__device__ __forceinline__ bf16 f2b(float x) { return __float2bfloat16(x); }
__device__ __forceinline__ unsigned short fbits(float x) { bf16 h = f2b(x); return *(unsigned short*)&h; }

// async global->LDS, 16B per lane. LDS dest must be wave-uniform base (HW adds lane*16).
__device__ __forceinline__ void gload16(const bf16* g, const short* l) {
    __builtin_amdgcn_global_load_lds(
        (const __attribute__((address_space(1))) unsigned int*)(unsigned long long)(g),
        (__attribute__((address_space(3))) unsigned int*)(unsigned long long)(l), 16, 0, 0);
}

// ---------------------------------------------------------------------------
// NT GEMM: C[m][n] = sum_k A[m][k]*B[n][k], A:[M,K] B:[N,K] bf16, K-major.
// 128x128 tile, 4 waves (2x2), mfma_16x16x32_bf16.
// T3/T4: 3 LDS buffers, prefetch depth 2, counted vmcnt (8/4/0), raw barriers.
// blockIdx.z = split-K chunk; EPI_F32 writes partial to outF + z*sOz.
// ---------------------------------------------------------------------------
template<int MODE>
__global__ __launch_bounds__(256)
void gemm_nt(const bf16* __restrict__ A, const bf16* __restrict__ Bm,
             int M, int N, int K, int Kspan, long long sOz,
             float* __restrict__ outF, bf16* __restrict__ outBf,
             const float* __restrict__ bias,
             const float* __restrict__ qkvb, const float* __restrict__ tnbp,
             bf16* __restrict__ Qb, bf16* __restrict__ Kb, bf16* __restrict__ Vb)
{
    __shared__ short Asl[3][128*32];
    __shared__ short Bsl[3][128*32];
    const int tid  = threadIdx.x;
    const int m0   = blockIdx.y * 128;
    const int n0   = blockIdx.x * 128;
    const int kbase= blockIdx.z * Kspan;
    const int lane = tid & 63, w = tid >> 6;
    const int wm   = (w >> 1) * 64, wn = (w & 1) * 64;
    const int fr   = lane & 15, kc = (lane >> 4) * 8;
    const int srow = lane >> 2, schk = (lane & 3) * 8;

    const bf16* Ag = A  + (long long)m0 * K + kbase;
    const bf16* Bg = Bm + (long long)n0 * K + kbase;

    f32x4 acc[4][4];
#pragma unroll
    for (int i = 0; i < 4; i++)
#pragma unroll
        for (int j = 0; j < 4; j++) acc[i][j] = (f32x4){0.f,0.f,0.f,0.f};

    auto stage = [&](int buf, int k0) {
        gload16(Ag + (long long)(w*32      + srow)*K + k0 + schk, &Asl[buf][(w*32     )*32]);
        gload16(Ag + (long long)(w*32 + 16 + srow)*K + k0 + schk, &Asl[buf][(w*32 + 16)*32]);
        gload16(Bg + (long long)(w*32      + srow)*K + k0 + schk, &Bsl[buf][(w*32     )*32]);
        gload16(Bg + (long long)(w*32 + 16 + srow)*K + k0 + schk, &Bsl[buf][(w*32 + 16)*32]);
    };

    const int nt = Kspan >> 5;
    stage(0, 0);
    stage(1, 32);
    for (int t = 0; t < nt; t++) {
        const int buf = t % 3;
        if (t + 2 < nt) {
            stage((t + 2) % 3, (t + 2) * 32);
            asm volatile("s_waitcnt vmcnt(8)" ::: "memory");   // oldest 4 (tile t) landed
        } else if (t + 1 < nt) {
            asm volatile("s_waitcnt vmcnt(4)" ::: "memory");
        } else {
            asm volatile("s_waitcnt vmcnt(0)" ::: "memory");
        }
        __builtin_amdgcn_s_barrier();                           // all waves' t-loads landed
        __builtin_amdgcn_sched_barrier(0);
        bf16x8 af[4], bfm[4];
#pragma unroll
        for (int i = 0; i < 4; i++) af[i]  = *(const bf16x8*)&Asl[buf][(wm + i*16 + fr)*32 + kc];
#pragma unroll
        for (int j = 0; j < 4; j++) bfm[j] = *(const bf16x8*)&Bsl[buf][(wn + j*16 + fr)*32 + kc];
#pragma unroll
        for (int i = 0; i < 4; i++)
#pragma unroll
            for (int j = 0; j < 4; j++)
                acc[i][j] = __builtin_amdgcn_mfma_f32_16x16x32_bf16(af[i], bfm[j], acc[i][j], 0, 0, 0);
        __builtin_amdgcn_s_barrier();                           // protect buf before re-stage
        __builtin_amdgcn_sched_barrier(0);
    }

    const int rq = (lane >> 4) * 4;
#pragma unroll
    for (int i = 0; i < 4; i++) {
        const int r0 = m0 + wm + i*16 + rq;
        int b2r = 0, s20 = 0, hdV = 0, dd0 = 0;
        float bvv[4];
        if (MODE == EPI_QKV) { b2r = r0 / NS; s20 = r0 - b2r*NS; }
        if (MODE == EPI_VT) {
            hdV = r0 >> 8; dd0 = r0 & 255;
#pragma unroll
            for (int rg = 0; rg < 4; rg++) {
                const int rr = r0 + rg;
                bvv[rg] = (rr < 512) ? qkvb[1024 + rr] : tnbp[2048 + rr - 512];
            }
        }
#pragma unroll
        for (int j = 0; j < 4; j++) {
            const int c = n0 + wn + j*16 + fr;
            if (MODE == EPI_F32) {
#pragma unroll
                for (int rg = 0; rg < 4; rg++)
                    outF[(long long)blockIdx.z * sOz + (long long)(r0+rg)*N + c] = acc[i][j][rg];
            } else if (MODE == EPI_RELU_BF) {
                const float bv = bias[c];
#pragma unroll
                for (int rg = 0; rg < 4; rg++)
                    outBf[(long long)(r0+rg)*N + c] = f2b(fmaxf(acc[i][j][rg] + bv, 0.f));
            } else if (MODE == EPI_QKV) {
                const int x  = (c >= 1536);
                const int c1 = c - x*1536;
                const int hd = c1 >> 8, dd = c1 & 255;
                const float bv = (c1 < 512) ? qkvb[x*512 + c1] : tnbp[x*1024 + (c1 - 512)];
                bf16* dst = x ? Kb : Qb;
#pragma unroll
                for (int rg = 0; rg < 4; rg++) {
                    int bb = b2r, ss = s20 + rg;
                    if (ss >= NS) { bb++; ss -= NS; }
                    dst[((long long)((bb*NH + hd)*SP + ss))*ND + dd] = f2b(acc[i][j][rg] + bv);
                }
            } else { // EPI_VT: rows = V output dim, cols = tokens; Vt[z][d][s]
                const int b2 = c / NS;
                const int s2 = c - b2*NS;
                const long long base = ((long long)((b2*NH + hdV)*ND + dd0))*SP + s2;
#pragma unroll
                for (int rg = 0; rg < 4; rg++)
                    Vb[base + (long long)rg*SP] = f2b(acc[i][j][rg] + bvv[rg]);
            }
        }
    }
}

// ---------------------------------------------------------------------------
// Fused attention v2: block = (z, 64-query quarter); grid (192, 4) so the 4
// same-z blocks share an XCD (flat ids differ by 192 = 0 mod 8) -> K/V L2 hits.
// Both phases: 2-buffer counted-vmcnt pipeline (no mid-loop vmcnt(0) drain).
// ---------------------------------------------------------------------------
__global__ __launch_bounds__(256)
void attn_fused(const bf16* __restrict__ Qb, const bf16* __restrict__ Kb,
                const bf16* __restrict__ Vtb, const int* __restrict__ tokens,
                bf16* __restrict__ ctx)
{
    // 2 staging bufs of (Ks 16KB + Qs 4KB) | red 1KB | maskv 1KB | P 33KB
    __shared__ __align__(16) char smem[2*20480 + 1024 + 1024 + 64*PSTR*2];
    float* red   = (float*)(smem + 40960);
    float* maskv = (float*)(smem + 40960 + 1024);
    short* P     = (short*)(smem + 40960 + 2048);

    const int z  = blockIdx.x;
    const int b  = z / NH, h = z - b*NH;
    const int q0 = blockIdx.y * 64;
    const int tid = threadIdx.x;
    const int lane = tid & 63, w = tid >> 6;
    const int fr = lane & 15, qh = lane >> 4;
    const int kc = qh * 8;
    const int srow = lane >> 2, schk = (lane & 3) * 8;

    const bf16* Kp = Kb  + (long long)z * SLAB;
    const bf16* Qp = Qb  + (long long)z * SLAB;
    const bf16* Vp = Vtb + (long long)z * SLAB;

    {
        const int s = tid;
        float mv = -1e9f;
        if (s < NS && tokens[b*NS + s] != 0) mv = 0.f;
        maskv[s] = mv;
    }

    // ---- phase 1: S^T[s][q] = sum_d K[s,d] Q[q,d], 8 d-chunks of 32 ----
    auto stage1 = [&](int buf, int k0) {
        short* Ks = (short*)(smem + buf*20480);
        short* Qs = (short*)(smem + buf*20480 + 16384);
#pragma unroll
        for (int r2 = 0; r2 < 4; r2++)
            gload16(Kp + (long long)(w*64 + r2*16 + srow)*ND + k0 + schk, &Ks[(w*64 + r2*16)*32]);
        gload16(Qp + (long long)(q0 + w*16 + srow)*ND + k0 + schk, &Qs[(w*16)*32]);
    };

    f32x4 acc[4][4];
#pragma unroll
    for (int i = 0; i < 4; i++)
#pragma unroll
        for (int j = 0; j < 4; j++) acc[i][j] = (f32x4){0.f,0.f,0.f,0.f};

    stage1(0, 0);
    for (int t = 0; t < 8; t++) {
        const int buf = t & 1;
        if (t + 1 < 8) {
            stage1(buf ^ 1, (t + 1) * 32);
            asm volatile("s_waitcnt vmcnt(5)" ::: "memory");   // this wave's chunk-t loads landed
        } else {
            asm volatile("s_waitcnt vmcnt(0)" ::: "memory");
        }
        __builtin_amdgcn_s_barrier();
        __builtin_amdgcn_sched_barrier(0);
        const short* Ks = (const short*)(smem + buf*20480);
        const short* Qs = (const short*)(smem + buf*20480 + 16384);
        bf16x8 ak[4], bq[4];
#pragma unroll
        for (int i = 0; i < 4; i++) ak[i] = *(const bf16x8*)&Ks[(w*64 + i*16 + fr)*32 + kc];
#pragma unroll
        for (int j = 0; j < 4; j++) bq[j] = *(const bf16x8*)&Qs[(j*16 + fr)*32 + kc];
#pragma unroll
        for (int i = 0; i < 4; i++)
#pragma unroll
            for (int j = 0; j < 4; j++)
                acc[i][j] = __builtin_amdgcn_mfma_f32_16x16x32_bf16(ak[i], bq[j], acc[i][j], 0, 0, 0);
        __builtin_amdgcn_s_barrier();                           // buf free for re-stage
        __builtin_amdgcn_sched_barrier(0);
    }

    // ---- softmax over s per column q ----
    float mk[4][4];
#pragma unroll
    for (int i = 0; i < 4; i++)
#pragma unroll
        for (int rg = 0; rg < 4; rg++) mk[i][rg] = maskv[w*64 + i*16 + qh*4 + rg];
#pragma unroll
    for (int i = 0; i < 4; i++)
#pragma unroll
        for (int j = 0; j < 4; j++)
#pragma unroll
            for (int rg = 0; rg < 4; rg++)
                acc[i][j][rg] = acc[i][j][rg] * 0.0625f + mk[i][rg];

    float pm[4];
#pragma unroll
    for (int j = 0; j < 4; j++) {
        float m = -3.0e38f;
#pragma unroll
        for (int i = 0; i < 4; i++)
#pragma unroll
            for (int rg = 0; rg < 4; rg++) m = fmaxf(m, acc[i][j][rg]);
        m = fmaxf(m, __shfl_xor(m, 16));
        m = fmaxf(m, __shfl_xor(m, 32));
        pm[j] = m;
    }
#pragma unroll
    for (int j = 0; j < 4; j++) red[w*64 + j*16 + fr] = pm[j];
    __syncthreads();
    float gm[4];
#pragma unroll
    for (int j = 0; j < 4; j++)
        gm[j] = fmaxf(fmaxf(red[j*16 + fr], red[64 + j*16 + fr]),
                      fmaxf(red[128 + j*16 + fr], red[192 + j*16 + fr]));
    float ps[4] = {0.f, 0.f, 0.f, 0.f};
#pragma unroll
    for (int i = 0; i < 4; i++)
#pragma unroll
        for (int j = 0; j < 4; j++)
#pragma unroll
            for (int rg = 0; rg < 4; rg++) {
                float e = __expf(acc[i][j][rg] - gm[j]);
                acc[i][j][rg] = e;
                ps[j] += e;
            }
#pragma unroll
    for (int j = 0; j < 4; j++) {
        ps[j] += __shfl_xor(ps[j], 16);
        ps[j] += __shfl_xor(ps[j], 32);
    }
    __syncthreads();
#pragma unroll
    for (int j = 0; j < 4; j++) red[w*64 + j*16 + fr] = ps[j];
    __syncthreads();
    float inv[4];
#pragma unroll
    for (int j = 0; j < 4; j++)
        inv[j] = 1.f / (red[j*16 + fr] + red[64 + j*16 + fr] + red[128 + j*16 + fr] + red[192 + j*16 + fr]);

#pragma unroll
    for (int i = 0; i < 4; i++)
#pragma unroll
        for (int j = 0; j < 4; j++) {
            ushort4 pk;
            pk.x = fbits(acc[i][j][0] * inv[j]);
            pk.y = fbits(acc[i][j][1] * inv[j]);
            pk.z = fbits(acc[i][j][2] * inv[j]);
            pk.w = fbits(acc[i][j][3] * inv[j]);
            *(ushort4*)&P[(j*16 + fr)*PSTR + w*64 + i*16 + qh*4] = pk;
        }
    __syncthreads();   // P visible to all waves; drains before phase-2 staging starts

    // ---- phase 2: ctx[q][d] = sum_s P[q,s] Vt[d,s], 7 s-chunks of 32 ----
    auto stage2 = [&](int buf, int s0) {
        short* Vs = (short*)(smem + buf*20480);
#pragma unroll
        for (int r2 = 0; r2 < 4; r2++)
            gload16(Vp + (long long)(w*64 + r2*16 + srow)*SP + s0 + schk, &Vs[(w*64 + r2*16)*32]);
    };

    f32x4 acc2[4][4];
#pragma unroll
    for (int i = 0; i < 4; i++)
#pragma unroll
        for (int j = 0; j < 4; j++) acc2[i][j] = (f32x4){0.f,0.f,0.f,0.f};

    stage2(0, 0);
    for (int t = 0; t < 7; t++) {
        const int buf = t & 1;
        if (t + 1 < 7) {
            stage2(buf ^ 1, (t + 1) * 32);
            asm volatile("s_waitcnt vmcnt(4)" ::: "memory");
        } else {
            asm volatile("s_waitcnt vmcnt(0)" ::: "memory");
        }
        __builtin_amdgcn_s_barrier();
        __builtin_amdgcn_sched_barrier(0);
        const short* Vs = (const short*)(smem + buf*20480);
        bf16x8 ap[4], bv[4];
#pragma unroll
        for (int i = 0; i < 4; i++) ap[i] = *(const bf16x8*)&P[(i*16 + fr)*PSTR + t*32 + kc];
#pragma unroll
        for (int j = 0; j < 4; j++) bv[j] = *(const bf16x8*)&Vs[(w*64 + j*16 + fr)*32 + kc];
#pragma unroll
        for (int i = 0; i < 4; i++)
#pragma unroll
            for (int j = 0; j < 4; j++)
                acc2[i][j] = __builtin_amdgcn_mfma_f32_16x16x32_bf16(ap[i], bv[j], acc2[i][j], 0, 0, 0);
        __builtin_amdgcn_s_barrier();
        __builtin_amdgcn_sched_barrier(0);
    }

#pragma unroll
    for (int i = 0; i < 4; i++)
#pragma unroll
        for (int j = 0; j < 4; j++)
#pragma unroll
            for (int rg = 0; rg < 4; rg++) {
                const int qg = q0 + i*16 + qh*4 + rg;
                if (qg < NS) {
                    const int d = w*64 + j*16 + fr;
                    ctx[((long long)(b*NS + qg))*1536 + h*256 + d] = f2b(acc2[i][j][rg]);
                }
            }
}

// ---------------------------------------------------------------------------
__global__ void embed_kernel(const int* __restrict__ tokens, const float* __restrict__ tok_emb,
                             const float* __restrict__ pos_emb, float* __restrict__ hf,
                             bf16* __restrict__ hbf)
{
    long long id = (long long)blockIdx.x * 256 + threadIdx.x;
    if (id >= (long long)NBS * ND) return;
    long long r = id >> 8;
    int j = id & 255;
    int tk = tokens[r];
    int s  = (int)(r % NS);
    float v = tok_emb[(long long)tk * ND + j] + pos_emb[s * ND + j];
    hf[id]  = v;
    hbf[id] = f2b(v);
}

__global__ void transpose_w(const float* __restrict__ in, bf16* __restrict__ out,
                            int L, int R, int C, long long total)
{
    long long id = (long long)blockIdx.x * 256 + threadIdx.x;
    if (id >= total) return;
    int l = (int)(id / ((long long)R * C));
    long long rem = id - (long long)l * R * C;
    int c = (int)(rem / R);
    int r = (int)(rem - (long long)c * R);
    out[id] = f2b(in[((long long)l * R + r) * C + c]);
}

__global__ void pack_cls(const float* __restrict__ wqkv, bf16* __restrict__ wcat)
{
    long long id = (long long)blockIdx.x * 256 + threadIdx.x;
    if (id >= 24ll * 512 * 256) return;
    int lx = (int)(id / (512 * 256));
    int rem = (int)(id - (long long)lx * 512 * 256);
    int n = rem >> 8;
    int k = rem & 255;
    wcat[((long long)lx * 1536 + n) * 256 + k] = f2b(wqkv[((long long)lx * 256 + k) * 512 + n]);
}

__global__ __launch_bounds__(256)
void build_wtns(const float* __restrict__ A1, const float* __restrict__ A2,
                const float* __restrict__ A3, const float* __restrict__ A4,
                bf16* __restrict__ wcat)
{
    int lx = blockIdx.x;
    __shared__ float a1s[32], a2s[128], a3s[128], a4s[32];
    int t = threadIdx.x;
    if (t < 32)  { a1s[t] = A1[lx*32 + t]; a4s[t] = A4[lx*32 + t]; }
    if (t < 128) { a2s[t] = A2[lx*128 + t]; a3s[t] = A3[lx*128 + t]; }
    __syncthreads();
    int d = t;
    int p = d >> 6, q = (d >> 4) & 3, rr = (d >> 2) & 3, tt = d & 3;
    for (int i = 0; i < 4; i++) {
        float w1_0 = a1s[(p*2 + 0)*4 + i];
        float w1_1 = a1s[(p*2 + 1)*4 + i];
        for (int j = 0; j < 8; j++) {
            float c1_0 = w1_0 * a2s[((q*2+0)*2+0)*8 + j] + w1_1 * a2s[((q*2+1)*2+0)*8 + j];
            float c1_1 = w1_0 * a2s[((q*2+0)*2+1)*8 + j] + w1_1 * a2s[((q*2+1)*2+1)*8 + j];
            for (int kk = 0; kk < 8; kk++) {
                float c2_0 = c1_0 * a3s[((rr*2+0)*2+0)*8 + kk] + c1_1 * a3s[((rr*2+1)*2+0)*8 + kk];
                float c2_1 = c1_0 * a3s[((rr*2+0)*2+1)*8 + kk] + c1_1 * a3s[((rr*2+1)*2+1)*8 + kk];
                for (int ll = 0; ll < 4; ll++) {
                    float sv = c2_0 * a4s[(tt*2 + 0)*4 + ll] + c2_1 * a4s[(tt*2 + 1)*4 + ll];
                    int e = ((i*8 + j)*8 + kk)*4 + ll;
                    wcat[((long long)lx * 1536 + 512 + e) * 256 + d] = f2b(sv);
                }
            }
        }
    }
}

// out = LN(resid + raw0 + raw1 + bias) * g + b
__global__ __launch_bounds__(256)
void ln_kernel(const float* __restrict__ raw0, const float* __restrict__ raw1,
               const float* __restrict__ bias, const float* __restrict__ resid,
               const float* __restrict__ g, const float* __restrict__ bb,
               float* __restrict__ outF, bf16* __restrict__ outBf)
{
    int w = threadIdx.x >> 6, lane = threadIdx.x & 63;
    long long r = (long long)blockIdx.x * 4 + w;
    long long base = r * ND;
    float x[4]; float s = 0.f;
#pragma unroll
    for (int c = 0; c < 4; c++) {
        int j = lane + 64*c;
        x[c] = resid[base + j] + raw0[base + j] + raw1[base + j] + bias[j];
        s += x[c];
    }
#pragma unroll
    for (int o = 32; o; o >>= 1) s += __shfl_xor(s, o);
    float mean = s * (1.f/256.f);
    float vs = 0.f;
#pragma unroll
    for (int c = 0; c < 4; c++) { float d = x[c] - mean; vs += d*d; }
#pragma unroll
    for (int o = 32; o; o >>= 1) vs += __shfl_xor(vs, o);
    float rs = rsqrtf(vs * (1.f/256.f) + 1e-6f);
#pragma unroll
    for (int c = 0; c < 4; c++) {
        int j = lane + 64*c;
        float y = (x[c] - mean) * rs * g[j] + bb[j];
        outF[base + j]  = y;
        outBf[base + j] = f2b(y);
    }
}

// ---------------------------------------------------------------------------
extern "C" void kernel_launch(void* const* d_in, const int* in_sizes, int n_in,
                              void* d_out, int out_size, void* d_ws, size_t ws_size,
                              hipStream_t stream)
{
    const int*   tokens  = (const int*)  d_in[0];
    const float* tok_emb = (const float*)d_in[1];
    const float* pos_emb = (const float*)d_in[2];
    const float* wqkv_w  = (const float*)d_in[3];
    const float* wqkv_b  = (const float*)d_in[4];
    const float* A1      = (const float*)d_in[5];
    const float* A2      = (const float*)d_in[6];
    const float* A3      = (const float*)d_in[7];
    const float* A4      = (const float*)d_in[8];
    const float* tnb     = (const float*)d_in[9];
    const float* out_w   = (const float*)d_in[10];
    const float* out_b   = (const float*)d_in[11];
    const float* ff1_w   = (const float*)d_in[12];
    const float* ff1_b   = (const float*)d_in[13];
    const float* ff2_w   = (const float*)d_in[14];
    const float* ff2_b   = (const float*)d_in[15];
    const float* ln1_g   = (const float*)d_in[16];
    const float* ln1_b   = (const float*)d_in[17];
    const float* ln2_g   = (const float*)d_in[18];
    const float* ln2_b   = (const float*)d_in[19];

    char* ws = (char*)d_ws;
    size_t off = 0;
    auto alloc = [&](size_t bytes) -> char* {
        char* p = ws + off;
        off += (bytes + 255) & ~(size_t)255;
        return p;
    };
    float* hf    = (float*)alloc((size_t)NBS * ND * 4);
    bf16*  hbf   = (bf16*) alloc((size_t)NBS * ND * 2);
    bf16*  wcat  = (bf16*) alloc(24ull * 1536 * 256 * 2);
    bf16*  owt   = (bf16*) alloc(8ull * 256 * 1536 * 2);
    bf16*  f1wt  = (bf16*) alloc(8ull * 1024 * 256 * 2);
    bf16*  f2wt  = (bf16*) alloc(8ull * 256 * 1024 * 2);
    bf16*  Qb    = (bf16*) alloc((size_t)NZ * SLAB * 2);
    bf16*  Kb    = (bf16*) alloc((size_t)NZ * SLAB * 2);
    bf16*  Vtb   = (bf16*) alloc((size_t)NZ * SLAB * 2);
    bf16*  ctxg  = (bf16*) alloc((size_t)NBS * 1536 * 2);
    bf16*  ffn   = (bf16*) alloc((size_t)NBS * 1024 * 2);
    float* raw   = (float*)alloc((size_t)NBS * ND * 4 * 2);   // 2 split-K partials
    float* out1f = (float*)alloc((size_t)NBS * ND * 4);
    bf16*  out1bf= (bf16*) alloc((size_t)NBS * ND * 2);
    if (off > ws_size) return;
    float* raw1 = raw + (size_t)NBS * ND;

    // zero Q/K/Vt pads once (pad rows/cols never rewritten)
    hipMemsetAsync(Qb,  0, (size_t)NZ * SLAB * 2, stream);
    hipMemsetAsync(Kb,  0, (size_t)NZ * SLAB * 2, stream);
    hipMemsetAsync(Vtb, 0, (size_t)NZ * SLAB * 2, stream);

    embed_kernel<<<NBS, 256, 0, stream>>>(tokens, tok_emb, pos_emb, hf, hbf);
    pack_cls<<<12288, 256, 0, stream>>>(wqkv_w, wcat);
    build_wtns<<<24, 256, 0, stream>>>(A1, A2, A3, A4, wcat);
    transpose_w<<<12288, 256, 0, stream>>>(out_w, owt, 8, 1536, 256, 8ll*1536*256);
    transpose_w<<<8192, 256, 0, stream>>>(ff1_w, f1wt, 8, 256, 1024, 8ll*256*1024);
    transpose_w<<<8192, 256, 0, stream>>>(ff2_w, f2wt, 8, 1024, 256, 8ll*1024*256);

    for (int l = 0; l < NL; l++) {
        const bf16* wl = wcat + (long long)l * 3 * 1536 * 256;
        // Q,K projection: [6400,256] @ [3072,256]^T -> Q/K slabs [z][s][d]
        gemm_nt<EPI_QKV><<<dim3(24, 50, 1), 256, 0, stream>>>(
            hbf, wl, NBS, 3072, 256, 256, 0, nullptr, nullptr, nullptr,
            wqkv_b + l * 3 * 512, tnb + l * 3 * 1024, Qb, Kb, nullptr);
        // V^T projection: [1536,256] @ [6400,256]^T -> Vt [z][d][s]
        gemm_nt<EPI_VT><<<dim3(50, 12, 1), 256, 0, stream>>>(
            wl + 2ll * 1536 * 256, hbf, 1536, NBS, 256, 256, 0, nullptr, nullptr, nullptr,
            wqkv_b + l * 3 * 512, tnb + l * 3 * 1024, nullptr, nullptr, Vtb);
        // fused attention -> ctxg [6400][1536]
        attn_fused<<<dim3(NZ, 4), 256, 0, stream>>>(Qb, Kb, Vtb, tokens, ctxg);
        // out projection, split-K=2 partials (no atomics)
        gemm_nt<EPI_F32><<<dim3(2, 50, 2), 256, 0, stream>>>(
            ctxg, owt + (long long)l * 256 * 1536, NBS, 256, 1536, 768, (long long)NBS*ND,
            raw, nullptr, nullptr, nullptr, nullptr, nullptr, nullptr, nullptr);
        ln_kernel<<<1600, 256, 0, stream>>>(raw, raw1, out_b + l * 256, hf,
                                            ln1_g + l * 256, ln1_b + l * 256, out1f, out1bf);
        // FFN
        gemm_nt<EPI_RELU_BF><<<dim3(8, 50, 1), 256, 0, stream>>>(
            out1bf, f1wt + (long long)l * 1024 * 256, NBS, 1024, 256, 256, 0,
            nullptr, ffn, ff1_b + l * 1024, nullptr, nullptr, nullptr, nullptr, nullptr);
        gemm_nt<EPI_F32><<<dim3(2, 50, 2), 256, 0, stream>>>(
            ffn, f2wt + (long long)l * 256 * 1024, NBS, 256, 1024, 512, (long long)NBS*ND,
            raw, nullptr, nullptr, nullptr, nullptr, nullptr, nullptr, nullptr);
        ln_kernel<<<1600, 256, 0, stream>>>(raw, raw1, ff2_b + l * 256, out1f,
                                            ln2_g + l * 256, ln2_b + l * 256,
                                            (l == NL - 1) ? (float*)d_out : hf, hbf);
    }
}

// Round 6
// 1019.267 us; speedup vs baseline: 1.7043x; 1.0259x over previous
//
#include <hip/hip_runtime.h>
#include <hip/hip_bf16.h>

typedef __bf16 bf16x8 __attribute__((ext_vector_type(8)));
typedef float f32x4 __attribute__((ext_vector_type(4)));

#define NB 32
#define NS 200
#define SP 256
#define ND 256
#define NH 6
#define NL 8
#define NBS (NB*NS)      // 6400
#define NZ (NB*NH)       // 192
#define SLAB (SP*ND)     // 65536
#define PSTR 264         // P lds row stride (shorts)

using bf16 = __hip_bfloat16;

enum { EPI_F32 = 0, EPI_RELU_BF = 1, EPI_QKVT = 2 };

__device__ __forceinline__ float b2f(bf16 x) { return __bfloat162float(x); }
__device__ __forceinline__ bf16 f2b(float x) { return __float2bfloat16(x); }
__device__ __forceinline__ unsigned short fbits(float x) { bf16 h = f2b(x); return *(unsigned short*)&h; }

// async global->LDS, 16B per lane. LDS dest must be wave-uniform base (HW adds lane*16).
__device__ __forceinline__ void gload16(const bf16* g, const short* l) {
    __builtin_amdgcn_global_load_lds(
        (const __attribute__((address_space(1))) unsigned int*)(unsigned long long)(g),
        (__attribute__((address_space(3))) unsigned int*)(unsigned long long)(l), 16, 0, 0);
}

// ---------------------------------------------------------------------------
// NT GEMM: C[m][n] = sum_k A[m][k]*B[n][k], A:[M,K] B:[N,K] bf16, K-major.
// 128x128 tile, 4 waves (2x2), mfma_16x16x32_bf16.
// T3/T4: 3 LDS buffers, prefetch depth 2, counted vmcnt (8/4/0), raw barriers.
// blockIdx.z = split-K chunk; EPI_F32 writes partial to outF + z*sOz.
// EPI_QKVT: A=qkv weights (M=4608 dims), B=activations (N=6400 tokens);
//           rows 0..1535 -> Q[z][s][d], 1536..3071 -> K[z][s][d],
//           3072..4607 -> Vt[z][d][s].
// ---------------------------------------------------------------------------
template<int MODE>
__global__ __launch_bounds__(256)
void gemm_nt(const bf16* __restrict__ A, const bf16* __restrict__ Bm,
             int M, int N, int K, int Kspan, long long sOz,
             float* __restrict__ outF, bf16* __restrict__ outBf,
             const float* __restrict__ bias,
             const float* __restrict__ qkvb, const float* __restrict__ tnbp,
             bf16* __restrict__ Qb, bf16* __restrict__ Kb, bf16* __restrict__ Vb)
{
    __shared__ short Asl[3][128*32];
    __shared__ short Bsl[3][128*32];
    const int tid  = threadIdx.x;
    const int m0   = blockIdx.y * 128;
    const int n0   = blockIdx.x * 128;
    const int kbase= blockIdx.z * Kspan;
    const int lane = tid & 63, w = tid >> 6;
    const int wm   = (w >> 1) * 64, wn = (w & 1) * 64;
    const int fr   = lane & 15, kc = (lane >> 4) * 8;
    const int srow = lane >> 2, schk = (lane & 3) * 8;

    const bf16* Ag = A  + (long long)m0 * K + kbase;
    const bf16* Bg = Bm + (long long)n0 * K + kbase;

    f32x4 acc[4][4];
#pragma unroll
    for (int i = 0; i < 4; i++)
#pragma unroll
        for (int j = 0; j < 4; j++) acc[i][j] = (f32x4){0.f,0.f,0.f,0.f};

    auto stage = [&](int buf, int k0) {
        gload16(Ag + (long long)(w*32      + srow)*K + k0 + schk, &Asl[buf][(w*32     )*32]);
        gload16(Ag + (long long)(w*32 + 16 + srow)*K + k0 + schk, &Asl[buf][(w*32 + 16)*32]);
        gload16(Bg + (long long)(w*32      + srow)*K + k0 + schk, &Bsl[buf][(w*32     )*32]);
        gload16(Bg + (long long)(w*32 + 16 + srow)*K + k0 + schk, &Bsl[buf][(w*32 + 16)*32]);
    };

    const int nt = Kspan >> 5;
    stage(0, 0);
    stage(1, 32);
    for (int t = 0; t < nt; t++) {
        const int buf = t % 3;
        if (t + 2 < nt) {
            stage((t + 2) % 3, (t + 2) * 32);
            asm volatile("s_waitcnt vmcnt(8)" ::: "memory");   // oldest 4 (tile t) landed
        } else if (t + 1 < nt) {
            asm volatile("s_waitcnt vmcnt(4)" ::: "memory");
        } else {
            asm volatile("s_waitcnt vmcnt(0)" ::: "memory");
        }
        __builtin_amdgcn_s_barrier();                           // all waves' t-loads landed
        __builtin_amdgcn_sched_barrier(0);
        bf16x8 af[4], bfm[4];
#pragma unroll
        for (int i = 0; i < 4; i++) af[i]  = *(const bf16x8*)&Asl[buf][(wm + i*16 + fr)*32 + kc];
#pragma unroll
        for (int j = 0; j < 4; j++) bfm[j] = *(const bf16x8*)&Bsl[buf][(wn + j*16 + fr)*32 + kc];
#pragma unroll
        for (int i = 0; i < 4; i++)
#pragma unroll
            for (int j = 0; j < 4; j++)
                acc[i][j] = __builtin_amdgcn_mfma_f32_16x16x32_bf16(af[i], bfm[j], acc[i][j], 0, 0, 0);
        __builtin_amdgcn_s_barrier();                           // protect buf before re-stage
        __builtin_amdgcn_sched_barrier(0);
    }

    const int rq = (lane >> 4) * 4;
#pragma unroll
    for (int i = 0; i < 4; i++) {
        const int r0 = m0 + wm + i*16 + rq;
        int xq = 0, hdq = 0, dd0 = 0;
        float bvv[4];
        if (MODE == EPI_QKVT) {
            xq  = r0 / 1536;              // 0=Q 1=K 2=V (uniform across rg quad)
            const int c1 = r0 - xq*1536;
            hdq = c1 >> 8; dd0 = c1 & 255;
#pragma unroll
            for (int rg = 0; rg < 4; rg++) {
                const int cc = c1 + rg;
                bvv[rg] = (cc < 512) ? qkvb[xq*512 + cc] : tnbp[xq*1024 + cc - 512];
            }
        }
#pragma unroll
        for (int j = 0; j < 4; j++) {
            const int c = n0 + wn + j*16 + fr;
            if (MODE == EPI_F32) {
#pragma unroll
                for (int rg = 0; rg < 4; rg++)
                    outF[(long long)blockIdx.z * sOz + (long long)(r0+rg)*N + c] = acc[i][j][rg];
            } else if (MODE == EPI_RELU_BF) {
                const float bv = bias[c];
#pragma unroll
                for (int rg = 0; rg < 4; rg++)
                    outBf[(long long)(r0+rg)*N + c] = f2b(fmaxf(acc[i][j][rg] + bv, 0.f));
            } else { // EPI_QKVT: c = token index
                const int bb = c / NS;
                const int ss = c - bb*NS;
                if (xq == 2) {
                    // Vt[z][d][s], rg spans d -> stride SP
                    const long long base = ((long long)((bb*NH + hdq)*ND + dd0))*SP + ss;
#pragma unroll
                    for (int rg = 0; rg < 4; rg++)
                        Vb[base + (long long)rg*SP] = f2b(acc[i][j][rg] + bvv[rg]);
                } else {
                    // Q/K [z][s][d], rg spans d -> contiguous ushort4
                    bf16* dst = xq ? Kb : Qb;
                    ushort4 pk;
                    pk.x = fbits(acc[i][j][0] + bvv[0]);
                    pk.y = fbits(acc[i][j][1] + bvv[1]);
                    pk.z = fbits(acc[i][j][2] + bvv[2]);
                    pk.w = fbits(acc[i][j][3] + bvv[3]);
                    *(ushort4*)&dst[((long long)((bb*NH + hdq)*SP + ss))*ND + dd0] = pk;
                }
            }
        }
    }
}

// ---------------------------------------------------------------------------
// Fused attention: block = (z, 64-query quarter); grid (192, 4) so the 4
// same-z blocks share an XCD (flat ids differ by 192 = 0 mod 8) -> K/V L2 hits.
// Both phases: 2-buffer counted-vmcnt pipeline (no mid-loop vmcnt(0) drain).
// ---------------------------------------------------------------------------
__global__ __launch_bounds__(256)
void attn_fused(const bf16* __restrict__ Qb, const bf16* __restrict__ Kb,
                const bf16* __restrict__ Vtb, const int* __restrict__ tokens,
                bf16* __restrict__ ctx)
{
    // 2 staging bufs of (Ks 16KB + Qs 4KB) | red 1KB | maskv 1KB | P 33KB
    __shared__ __align__(16) char smem[2*20480 + 1024 + 1024 + 64*PSTR*2];
    float* red   = (float*)(smem + 40960);
    float* maskv = (float*)(smem + 40960 + 1024);
    short* P     = (short*)(smem + 40960 + 2048);

    const int z  = blockIdx.x;
    const int b  = z / NH, h = z - b*NH;
    const int q0 = blockIdx.y * 64;
    const int tid = threadIdx.x;
    const int lane = tid & 63, w = tid >> 6;
    const int fr = lane & 15, qh = lane >> 4;
    const int kc = qh * 8;
    const int srow = lane >> 2, schk = (lane & 3) * 8;

    const bf16* Kp = Kb  + (long long)z * SLAB;
    const bf16* Qp = Qb  + (long long)z * SLAB;
    const bf16* Vp = Vtb + (long long)z * SLAB;

    {
        const int s = tid;
        float mv = -1e9f;
        if (s < NS && tokens[b*NS + s] != 0) mv = 0.f;
        maskv[s] = mv;
    }

    // ---- phase 1: S^T[s][q] = sum_d K[s,d] Q[q,d], 8 d-chunks of 32 ----
    auto stage1 = [&](int buf, int k0) {
        short* Ks = (short*)(smem + buf*20480);
        short* Qs = (short*)(smem + buf*20480 + 16384);
#pragma unroll
        for (int r2 = 0; r2 < 4; r2++)
            gload16(Kp + (long long)(w*64 + r2*16 + srow)*ND + k0 + schk, &Ks[(w*64 + r2*16)*32]);
        gload16(Qp + (long long)(q0 + w*16 + srow)*ND + k0 + schk, &Qs[(w*16)*32]);
    };

    f32x4 acc[4][4];
#pragma unroll
    for (int i = 0; i < 4; i++)
#pragma unroll
        for (int j = 0; j < 4; j++) acc[i][j] = (f32x4){0.f,0.f,0.f,0.f};

    stage1(0, 0);
    for (int t = 0; t < 8; t++) {
        const int buf = t & 1;
        if (t + 1 < 8) {
            stage1(buf ^ 1, (t + 1) * 32);
            asm volatile("s_waitcnt vmcnt(5)" ::: "memory");   // this wave's chunk-t loads landed
        } else {
            asm volatile("s_waitcnt vmcnt(0)" ::: "memory");
        }
        __builtin_amdgcn_s_barrier();
        __builtin_amdgcn_sched_barrier(0);
        const short* Ks = (const short*)(smem + buf*20480);
        const short* Qs = (const short*)(smem + buf*20480 + 16384);
        bf16x8 ak[4], bq[4];
#pragma unroll
        for (int i = 0; i < 4; i++) ak[i] = *(const bf16x8*)&Ks[(w*64 + i*16 + fr)*32 + kc];
#pragma unroll
        for (int j = 0; j < 4; j++) bq[j] = *(const bf16x8*)&Qs[(j*16 + fr)*32 + kc];
#pragma unroll
        for (int i = 0; i < 4; i++)
#pragma unroll
            for (int j = 0; j < 4; j++)
                acc[i][j] = __builtin_amdgcn_mfma_f32_16x16x32_bf16(ak[i], bq[j], acc[i][j], 0, 0, 0);
        __builtin_amdgcn_s_barrier();                           // buf free for re-stage
        __builtin_amdgcn_sched_barrier(0);
    }

    // ---- softmax over s per column q ----
    float mk[4][4];
#pragma unroll
    for (int i = 0; i < 4; i++)
#pragma unroll
        for (int rg = 0; rg < 4; rg++) mk[i][rg] = maskv[w*64 + i*16 + qh*4 + rg];
#pragma unroll
    for (int i = 0; i < 4; i++)
#pragma unroll
        for (int j = 0; j < 4; j++)
#pragma unroll
            for (int rg = 0; rg < 4; rg++)
                acc[i][j][rg] = acc[i][j][rg] * 0.0625f + mk[i][rg];

    float pm[4];
#pragma unroll
    for (int j = 0; j < 4; j++) {
        float m = -3.0e38f;
#pragma unroll
        for (int i = 0; i < 4; i++)
#pragma unroll
            for (int rg = 0; rg < 4; rg++) m = fmaxf(m, acc[i][j][rg]);
        m = fmaxf(m, __shfl_xor(m, 16));
        m = fmaxf(m, __shfl_xor(m, 32));
        pm[j] = m;
    }
#pragma unroll
    for (int j = 0; j < 4; j++) red[w*64 + j*16 + fr] = pm[j];
    __syncthreads();
    float gm[4];
#pragma unroll
    for (int j = 0; j < 4; j++)
        gm[j] = fmaxf(fmaxf(red[j*16 + fr], red[64 + j*16 + fr]),
                      fmaxf(red[128 + j*16 + fr], red[192 + j*16 + fr]));
    float ps[4] = {0.f, 0.f, 0.f, 0.f};
#pragma unroll
    for (int i = 0; i < 4; i++)
#pragma unroll
        for (int j = 0; j < 4; j++)
#pragma unroll
            for (int rg = 0; rg < 4; rg++) {
                float e = __expf(acc[i][j][rg] - gm[j]);
                acc[i][j][rg] = e;
                ps[j] += e;
            }
#pragma unroll
    for (int j = 0; j < 4; j++) {
        ps[j] += __shfl_xor(ps[j], 16);
        ps[j] += __shfl_xor(ps[j], 32);
    }
    __syncthreads();
#pragma unroll
    for (int j = 0; j < 4; j++) red[w*64 + j*16 + fr] = ps[j];
    __syncthreads();
    float inv[4];
#pragma unroll
    for (int j = 0; j < 4; j++)
        inv[j] = 1.f / (red[j*16 + fr] + red[64 + j*16 + fr] + red[128 + j*16 + fr] + red[192 + j*16 + fr]);

#pragma unroll
    for (int i = 0; i < 4; i++)
#pragma unroll
        for (int j = 0; j < 4; j++) {
            ushort4 pk;
            pk.x = fbits(acc[i][j][0] * inv[j]);
            pk.y = fbits(acc[i][j][1] * inv[j]);
            pk.z = fbits(acc[i][j][2] * inv[j]);
            pk.w = fbits(acc[i][j][3] * inv[j]);
            *(ushort4*)&P[(j*16 + fr)*PSTR + w*64 + i*16 + qh*4] = pk;
        }
    __syncthreads();   // P visible to all waves; drains before phase-2 staging starts

    // ---- phase 2: ctx[q][d] = sum_s P[q,s] Vt[d,s], 7 s-chunks of 32 ----
    auto stage2 = [&](int buf, int s0) {
        short* Vs = (short*)(smem + buf*20480);
#pragma unroll
        for (int r2 = 0; r2 < 4; r2++)
            gload16(Vp + (long long)(w*64 + r2*16 + srow)*SP + s0 + schk, &Vs[(w*64 + r2*16)*32]);
    };

    f32x4 acc2[4][4];
#pragma unroll
    for (int i = 0; i < 4; i++)
#pragma unroll
        for (int j = 0; j < 4; j++) acc2[i][j] = (f32x4){0.f,0.f,0.f,0.f};

    stage2(0, 0);
    for (int t = 0; t < 7; t++) {
        const int buf = t & 1;
        if (t + 1 < 7) {
            stage2(buf ^ 1, (t + 1) * 32);
            asm volatile("s_waitcnt vmcnt(4)" ::: "memory");
        } else {
            asm volatile("s_waitcnt vmcnt(0)" ::: "memory");
        }
        __builtin_amdgcn_s_barrier();
        __builtin_amdgcn_sched_barrier(0);
        const short* Vs = (const short*)(smem + buf*20480);
        bf16x8 ap[4], bv[4];
#pragma unroll
        for (int i = 0; i < 4; i++) ap[i] = *(const bf16x8*)&P[(i*16 + fr)*PSTR + t*32 + kc];
#pragma unroll
        for (int j = 0; j < 4; j++) bv[j] = *(const bf16x8*)&Vs[(w*64 + j*16 + fr)*32 + kc];
#pragma unroll
        for (int i = 0; i < 4; i++)
#pragma unroll
            for (int j = 0; j < 4; j++)
                acc2[i][j] = __builtin_amdgcn_mfma_f32_16x16x32_bf16(ap[i], bv[j], acc2[i][j], 0, 0, 0);
        __builtin_amdgcn_s_barrier();
        __builtin_amdgcn_sched_barrier(0);
    }

#pragma unroll
    for (int i = 0; i < 4; i++)
#pragma unroll
        for (int j = 0; j < 4; j++)
#pragma unroll
            for (int rg = 0; rg < 4; rg++) {
                const int qg = q0 + i*16 + qh*4 + rg;
                if (qg < NS) {
                    const int d = w*64 + j*16 + fr;
                    ctx[((long long)(b*NS + qg))*1536 + h*256 + d] = f2b(acc2[i][j][rg]);
                }
            }
}

// ---------------------------------------------------------------------------
__global__ void embed_kernel(const int* __restrict__ tokens, const float* __restrict__ tok_emb,
                             const float* __restrict__ pos_emb, float* __restrict__ hf,
                             bf16* __restrict__ hbf)
{
    long long id = (long long)blockIdx.x * 256 + threadIdx.x;
    if (id >= (long long)NBS * ND) return;
    long long r = id >> 8;
    int j = id & 255;
    int tk = tokens[r];
    int s  = (int)(r % NS);
    float v = tok_emb[(long long)tk * ND + j] + pos_emb[s * ND + j];
    hf[id]  = v;
    hbf[id] = f2b(v);
}

// Tiled transpose: out[l][c*outStride + r] = in[l][r*C + c]  (f32 -> bf16)
// grid (C/32, R/32, L), block 256 (32x8), LDS 32x33.
__global__ __launch_bounds__(256)
void transpose_tile(const float* __restrict__ in, bf16* __restrict__ out,
                    int R, int C, long long inL, long long outL, int outStride)
{
    __shared__ float tl[32][33];
    const int l  = blockIdx.z;
    const int r0 = blockIdx.y * 32, c0 = blockIdx.x * 32;
    const float* ip = in + (long long)l * inL;
    bf16* op = out + (long long)l * outL;
    const int tx = threadIdx.x & 31, ty = threadIdx.x >> 5;
#pragma unroll
    for (int i = 0; i < 4; i++) {
        const int r = r0 + ty + i*8;
        tl[ty + i*8][tx] = ip[(long long)r * C + c0 + tx];
    }
    __syncthreads();
#pragma unroll
    for (int i = 0; i < 4; i++) {
        const int c = c0 + ty + i*8;
        op[(long long)c * outStride + r0 + tx] = f2b(tl[tx][ty + i*8]);
    }
}

__global__ __launch_bounds__(256)
void build_wtns(const float* __restrict__ A1, const float* __restrict__ A2,
                const float* __restrict__ A3, const float* __restrict__ A4,
                bf16* __restrict__ wcat)
{
    int lx = blockIdx.x;
    __shared__ float a1s[32], a2s[128], a3s[128], a4s[32];
    int t = threadIdx.x;
    if (t < 32)  { a1s[t] = A1[lx*32 + t]; a4s[t] = A4[lx*32 + t]; }
    if (t < 128) { a2s[t] = A2[lx*128 + t]; a3s[t] = A3[lx*128 + t]; }
    __syncthreads();
    int d = t;
    int p = d >> 6, q = (d >> 4) & 3, rr = (d >> 2) & 3, tt = d & 3;
    for (int i = 0; i < 4; i++) {
        float w1_0 = a1s[(p*2 + 0)*4 + i];
        float w1_1 = a1s[(p*2 + 1)*4 + i];
        for (int j = 0; j < 8; j++) {
            float c1_0 = w1_0 * a2s[((q*2+0)*2+0)*8 + j] + w1_1 * a2s[((q*2+1)*2+0)*8 + j];
            float c1_1 = w1_0 * a2s[((q*2+0)*2+1)*8 + j] + w1_1 * a2s[((q*2+1)*2+1)*8 + j];
            for (int kk = 0; kk < 8; kk++) {
                float c2_0 = c1_0 * a3s[((rr*2+0)*2+0)*8 + kk] + c1_1 * a3s[((rr*2+1)*2+0)*8 + kk];
                float c2_1 = c1_0 * a3s[((rr*2+0)*2+1)*8 + kk] + c1_1 * a3s[((rr*2+1)*2+1)*8 + kk];
                for (int ll = 0; ll < 4; ll++) {
                    float sv = c2_0 * a4s[(tt*2 + 0)*4 + ll] + c2_1 * a4s[(tt*2 + 1)*4 + ll];
                    int e = ((i*8 + j)*8 + kk)*4 + ll;
                    wcat[((long long)lx * 1536 + 512 + e) * 256 + d] = f2b(sv);
                }
            }
        }
    }
}

// out = LN(resid + raw0 + raw1 + bias) * g + b
__global__ __launch_bounds__(256)
void ln_kernel(const float* __restrict__ raw0, const float* __restrict__ raw1,
               const float* __restrict__ bias, const float* __restrict__ resid,
               const float* __restrict__ g, const float* __restrict__ bb,
               float* __restrict__ outF, bf16* __restrict__ outBf)
{
    int w = threadIdx.x >> 6, lane = threadIdx.x & 63;
    long long r = (long long)blockIdx.x * 4 + w;
    long long base = r * ND;
    float x[4]; float s = 0.f;
#pragma unroll
    for (int c = 0; c < 4; c++) {
        int j = lane + 64*c;
        x[c] = resid[base + j] + raw0[base + j] + raw1[base + j] + bias[j];
        s += x[c];
    }
#pragma unroll
    for (int o = 32; o; o >>= 1) s += __shfl_xor(s, o);
    float mean = s * (1.f/256.f);
    float vs = 0.f;
#pragma unroll
    for (int c = 0; c < 4; c++) { float d = x[c] - mean; vs += d*d; }
#pragma unroll
    for (int o = 32; o; o >>= 1) vs += __shfl_xor(vs, o);
    float rs = rsqrtf(vs * (1.f/256.f) + 1e-6f);
#pragma unroll
    for (int c = 0; c < 4; c++) {
        int j = lane + 64*c;
        float y = (x[c] - mean) * rs * g[j] + bb[j];
        outF[base + j]  = y;
        outBf[base + j] = f2b(y);
    }
}

// ---------------------------------------------------------------------------
extern "C" void kernel_launch(void* const* d_in, const int* in_sizes, int n_in,
                              void* d_out, int out_size, void* d_ws, size_t ws_size,
                              hipStream_t stream)
{
    const int*   tokens  = (const int*)  d_in[0];
    const float* tok_emb = (const float*)d_in[1];
    const float* pos_emb = (const float*)d_in[2];
    const float* wqkv_w  = (const float*)d_in[3];
    const float* wqkv_b  = (const float*)d_in[4];
    const float* A1      = (const float*)d_in[5];
    const float* A2      = (const float*)d_in[6];
    const float* A3      = (const float*)d_in[7];
    const float* A4      = (const float*)d_in[8];
    const float* tnb     = (const float*)d_in[9];
    const float* out_w   = (const float*)d_in[10];
    const float* out_b   = (const float*)d_in[11];
    const float* ff1_w   = (const float*)d_in[12];
    const float* ff1_b   = (const float*)d_in[13];
    const float* ff2_w   = (const float*)d_in[14];
    const float* ff2_b   = (const float*)d_in[15];
    const float* ln1_g   = (const float*)d_in[16];
    const float* ln1_b   = (const float*)d_in[17];
    const float* ln2_g   = (const float*)d_in[18];
    const float* ln2_b   = (const float*)d_in[19];

    char* ws = (char*)d_ws;
    size_t off = 0;
    auto alloc = [&](size_t bytes) -> char* {
        char* p = ws + off;
        off += (bytes + 255) & ~(size_t)255;
        return p;
    };
    float* hf    = (float*)alloc((size_t)NBS * ND * 4);
    bf16*  hbf   = (bf16*) alloc((size_t)NBS * ND * 2);
    bf16*  wcat  = (bf16*) alloc(24ull * 1536 * 256 * 2);
    bf16*  owt   = (bf16*) alloc(8ull * 256 * 1536 * 2);
    bf16*  f1wt  = (bf16*) alloc(8ull * 1024 * 256 * 2);
    bf16*  f2wt  = (bf16*) alloc(8ull * 256 * 1024 * 2);
    bf16*  Qb    = (bf16*) alloc((size_t)NZ * SLAB * 2);
    bf16*  Kb    = (bf16*) alloc((size_t)NZ * SLAB * 2);
    bf16*  Vtb   = (bf16*) alloc((size_t)NZ * SLAB * 2);
    bf16*  ctxg  = (bf16*) alloc((size_t)NBS * 1536 * 2);
    bf16*  ffn   = (bf16*) alloc((size_t)NBS * 1024 * 2);
    float* raw   = (float*)alloc((size_t)NBS * ND * 4 * 2);   // 2 split-K partials
    float* out1f = (float*)alloc((size_t)NBS * ND * 4);
    bf16*  out1bf= (bf16*) alloc((size_t)NBS * ND * 2);
    if (off > ws_size) return;
    float* raw1 = raw + (size_t)NBS * ND;

    // zero Q/K/Vt pads once (contiguous slabs; pad rows/cols never rewritten)
    hipMemsetAsync(Qb, 0, (size_t)3 * NZ * SLAB * 2, stream);

    embed_kernel<<<NBS, 256, 0, stream>>>(tokens, tok_emb, pos_emb, hf, hbf);
    // cls qkv heads: wqkv [24][256][512] -> wcat rows 0..511 per lx (stride 1536*256)
    transpose_tile<<<dim3(16, 8, 24), 256, 0, stream>>>(
        wqkv_w, wcat, 256, 512, 256ll*512, 1536ll*256, 256);
    build_wtns<<<24, 256, 0, stream>>>(A1, A2, A3, A4, wcat);
    transpose_tile<<<dim3(8, 48, 8), 256, 0, stream>>>(
        out_w, owt, 1536, 256, 1536ll*256, 256ll*1536, 1536);
    transpose_tile<<<dim3(32, 8, 8), 256, 0, stream>>>(
        ff1_w, f1wt, 256, 1024, 256ll*1024, 1024ll*256, 256);
    transpose_tile<<<dim3(8, 32, 8), 256, 0, stream>>>(
        ff2_w, f2wt, 1024, 256, 1024ll*256, 256ll*1024, 1024);

    for (int l = 0; l < NL; l++) {
        const bf16* wl = wcat + (long long)l * 3 * 1536 * 256;
        // merged QKV: A = qkv weights [4608,256], B = activations [6400,256]
        gemm_nt<EPI_QKVT><<<dim3(50, 36, 1), 256, 0, stream>>>(
            wl, hbf, 4608, NBS, 256, 256, 0, nullptr, nullptr, nullptr,
            wqkv_b + l * 3 * 512, tnb + l * 3 * 1024, Qb, Kb, Vtb);
        // fused attention -> ctxg [6400][1536]
        attn_fused<<<dim3(NZ, 4), 256, 0, stream>>>(Qb, Kb, Vtb, tokens, ctxg);
        // out projection, split-K=2 partials (no atomics)
        gemm_nt<EPI_F32><<<dim3(2, 50, 2), 256, 0, stream>>>(
            ctxg, owt + (long long)l * 256 * 1536, NBS, 256, 1536, 768, (long long)NBS*ND,
            raw, nullptr, nullptr, nullptr, nullptr, nullptr, nullptr, nullptr);
        ln_kernel<<<1600, 256, 0, stream>>>(raw, raw1, out_b + l * 256, hf,
                                            ln1_g + l * 256, ln1_b + l * 256, out1f, out1bf);
        // FFN
        gemm_nt<EPI_RELU_BF><<<dim3(8, 50, 1), 256, 0, stream>>>(
            out1bf, f1wt + (long long)l * 1024 * 256, NBS, 1024, 256, 256, 0,
            nullptr, ffn, ff1_b + l * 1024, nullptr, nullptr, nullptr, nullptr, nullptr);
        gemm_nt<EPI_F32><<<dim3(2, 50, 2), 256, 0, stream>>>(
            ffn, f2wt + (long long)l * 256 * 1024, NBS, 256, 1024, 512, (long long)NBS*ND,
            raw, nullptr, nullptr, nullptr, nullptr, nullptr, nullptr, nullptr);
        ln_kernel<<<1600, 256, 0, stream>>>(raw, raw1, ff2_b + l * 256, out1f,
                                            ln2_g + l * 256, ln2_b + l * 256,
                                            (l == NL - 1) ? (float*)d_out : hf, hbf);
    }
}